// Round 6
// baseline (519.455 us; speedup 1.0000x reference)
//
#include <hip/hip_runtime.h>

#define NN 100000
#define NE 6400000
#define BSZ 16                    // nodes per bucket
#define NBKT 6250                 // NN/BSZ exactly
#define NB 256                    // hist sub-chunks
#define CHUNK 25000               // NE/NB exactly
#define TOTBINS (NBKT * NB)       // 1,600,000
#define SC1 2048                  // elems per scan1 block
#define NCH ((TOTBINS + SC1 - 1) / SC1)   // 782
#define MCH 100000                // macro-chunk for passB (4 sub-chunks)
#define NMC 64                    // macro-chunks
#define NQ 1563                   // cursors per bucket-subset (ceil(NBKT/4))

// ============================ fast path ============================

// X[b*NBKT + k] = count of edges in sub-chunk b destined to bucket k
__global__ __launch_bounds__(512) void histA(const int* __restrict__ col, int* __restrict__ X) {
    __shared__ int h[NBKT];
    for (int i = threadIdx.x; i < NBKT; i += 512) h[i] = 0;
    __syncthreads();
    const int* c = col + blockIdx.x * CHUNK;
    for (int i = threadIdx.x; i < CHUNK; i += 512)
        atomicAdd(&h[__builtin_nontemporal_load(&c[i]) >> 4], 1);
    __syncthreads();
    int* o = X + blockIdx.x * NBKT;
    for (int i = threadIdx.x; i < NBKT; i += 512) o[i] = h[i];
}

// in-place exclusive scan over logical order idx = k*NB + b (storage X[b*NBKT+k])
__global__ __launch_bounds__(512) void scan1(int* __restrict__ X, int* __restrict__ ctot) {
    __shared__ int buf[SC1];
    __shared__ int ts[512];
    int base = blockIdx.x * SC1;
    for (int j = threadIdx.x; j < SC1; j += 512) {
        int idx = base + j; int v = 0;
        if (idx < TOTBINS) { int k = idx >> 8, b = idx & 255; v = X[b * NBKT + k]; }
        buf[j] = v;
    }
    __syncthreads();
    int j0 = threadIdx.x * 4;
    int a0 = buf[j0], a1 = buf[j0 + 1], a2 = buf[j0 + 2], a3 = buf[j0 + 3];
    int s = a0 + a1 + a2 + a3;
    ts[threadIdx.x] = s;
    __syncthreads();
    for (int off = 1; off < 512; off <<= 1) {
        int u = (threadIdx.x >= off) ? ts[threadIdx.x - off] : 0;
        __syncthreads();
        ts[threadIdx.x] += u;
        __syncthreads();
    }
    int e0 = ts[threadIdx.x] - s;
    int ev[4] = {e0, e0 + a0, e0 + a0 + a1, e0 + a0 + a1 + a2};
#pragma unroll
    for (int t = 0; t < 4; ++t) {
        int idx = base + j0 + t;
        if (idx < TOTBINS) { int k = idx >> 8, b = idx & 255; X[b * NBKT + k] = ev[t]; }
    }
    if (threadIdx.x == 511) ctot[blockIdx.x] = ts[511];
}

__global__ void scan2(const int* __restrict__ ctot, int* __restrict__ cbase) {
    __shared__ int ts[1024];
    int t = threadIdx.x;
    int orig = (t < NCH) ? ctot[t] : 0;
    ts[t] = orig;
    __syncthreads();
    for (int off = 1; off < 1024; off <<= 1) {
        int u = (t >= off) ? ts[t - off] : 0;
        __syncthreads();
        ts[t] += u;
        __syncthreads();
    }
    if (t < NCH) cbase[t] = ts[t] - orig;
}

__global__ __launch_bounds__(256) void scan3(int* __restrict__ X, const int* __restrict__ cbase) {
    int m = blockIdx.x * 256 + threadIdx.x;
    if (m >= TOTBINS) return;
    int b = m / NBKT;
    int k = m - b * NBKT;
    int idx = (k << 8) | b;
    X[m] += cbase[idx >> 11];     // SC1 = 2048
}

// 2D scatter: block = (macro-chunk c2, bucket-subset s). Runs of ~16 edges per
// (macro-chunk,bucket) are written by a single block -> ~full-line writes.
// Sibling blocks (same c2) share an XCD (bid&63 preserves bid%8) -> col/row L2 reuse.
__global__ __launch_bounds__(1024) void passB(const int* __restrict__ row, const int* __restrict__ col,
                                              const int* __restrict__ X, int* __restrict__ eb) {
    __shared__ int cur[NQ];
    int c2 = blockIdx.x & 63;
    int s  = blockIdx.x >> 6;
    int b0 = c2 * 4;                     // first sub-chunk of this macro-chunk
    for (int q = threadIdx.x; q < NQ; q += 1024) {
        int k = q * 4 + s;
        cur[q] = (k < NBKT) ? X[b0 * NBKT + k] : 0;
    }
    __syncthreads();
    const int* c = col + c2 * MCH;
    const int* r = row + c2 * MCH;
    for (int i = threadIdx.x; i < MCH; i += 1024) {
        int cc = c[i];
        int k = cc >> 4;
        if ((k & 3) == s) {
            int pos = atomicAdd(&cur[k >> 2], 1);
            eb[pos] = r[i] | ((cc & 15) << 17);
        }
    }
}

// degree (register cndmask count) -> dinv, fused with g1a/g1b = dinv * (x@W1) halves
__global__ __launch_bounds__(256) void passC(const int* __restrict__ eb, const int* __restrict__ X,
                                             const float* __restrict__ x, const float* __restrict__ W1,
                                             float* __restrict__ dinv, float* __restrict__ g1a,
                                             float* __restrict__ g1b) {
    __shared__ float sW[144];
    __shared__ int cdeg[4][16];
    for (int i = threadIdx.x; i < 144; i += 256) sW[i] = W1[i];
    int w = threadIdx.x >> 6, lane = threadIdx.x & 63;
    int k = blockIdx.x * 4 + w;
    if (k < NBKT) {
        int s = X[k], e = (k + 1 < NBKT) ? X[k + 1] : NE;
        int m4 = (lane & 3) * 4;
        int deg4[4] = {0, 0, 0, 0};
        for (int i = s + (lane >> 2); i < e; i += 16) {
            int p = __builtin_nontemporal_load(&eb[i]);
            int slot = (p >> 17) & 15;
#pragma unroll
            for (int t = 0; t < 4; ++t) deg4[t] += (slot == m4 + t) ? 1 : 0;
        }
#pragma unroll
        for (int d = 4; d < 64; d <<= 1)
#pragma unroll
            for (int t = 0; t < 4; ++t) deg4[t] += __shfl_xor(deg4[t], d);
        if (lane < 4)
#pragma unroll
            for (int t = 0; t < 4; ++t) cdeg[w][lane * 4 + t] = deg4[t];
    }
    __syncthreads();
    if (k < NBKT) {
        int node0 = k * BSZ;
        if (lane < 16) dinv[node0 + lane] = rsqrtf((float)cdeg[w][lane] + 1.f);
        int nd = lane >> 2, fq = lane & 3;
        int node = node0 + nd;
        float di = rsqrtf((float)cdeg[w][nd] + 1.f);
        float xr[9];
#pragma unroll
        for (int q = 0; q < 9; ++q) xr[q] = x[node * 9 + q];
        float4 o;
        float* op = &o.x;
#pragma unroll
        for (int j = 0; j < 4; ++j) {
            int f = fq * 4 + j;
            float a = 0.f;
#pragma unroll
            for (int q = 0; q < 9; ++q) a = fmaf(xr[q], sW[q * 16 + f], a);
            op[j] = a * di;
        }
        if (fq < 2) *(float4*)(g1a + node * 8 + fq * 4) = o;
        else        *(float4*)(g1b + node * 8 + (fq - 2) * 4) = o;
    }
}

// half of layer-1: register accumulate + relu + partial layer-2 dot.
// HALF=0: outv[n] = partial h2 (features 0-7). HALF=1: outv[n] = gg[n] = dinv*(h2a+partial).
template <int HALF>
__global__ __launch_bounds__(256) void passE(const int* __restrict__ eb, const int* __restrict__ X,
                                             const float* __restrict__ g1h, const float* __restrict__ dinv,
                                             const float* __restrict__ b1, const float* __restrict__ W2,
                                             const float* __restrict__ h2a, float* __restrict__ outv) {
    __shared__ float sb[8], sw[8];
    if (threadIdx.x < 8) {
        sb[threadIdx.x] = b1[HALF * 8 + threadIdx.x];
        sw[threadIdx.x] = W2[HALF * 8 + threadIdx.x];
    }
    __syncthreads();
    int w = threadIdx.x >> 6, lane = threadIdx.x & 63;
    int k = blockIdx.x * 4 + w;
    if (k >= NBKT) return;
    int s = X[k], e = (k + 1 < NBKT) ? X[k + 1] : NE;
    int j = lane & 3, ego = lane >> 2;
    float2 acc[16];
#pragma unroll
    for (int t = 0; t < 16; ++t) { acc[t].x = 0.f; acc[t].y = 0.f; }
    int nIter = (e - s + 15) >> 4;
    int i = s + ego;
    int p = (i < e) ? __builtin_nontemporal_load(&eb[i]) : -1;
    for (int it = 0; it < nIter; ++it) {
        int inext = i + 16;
        int pnext = (inext < e) ? __builtin_nontemporal_load(&eb[inext]) : -1;
        if (p >= 0) {
            int r = p & 0x1FFFF, slot = (p >> 17) & 15;
            float2 g = *(const float2*)(g1h + r * 8 + j * 2);
#pragma unroll
            for (int t = 0; t < 16; ++t) {
                float m = (slot == t) ? 1.f : 0.f;
                acc[t].x = fmaf(m, g.x, acc[t].x);
                acc[t].y = fmaf(m, g.y, acc[t].y);
            }
        }
        p = pnext; i = inext;
    }
#pragma unroll
    for (int d = 4; d < 64; d <<= 1)
#pragma unroll
        for (int t = 0; t < 16; ++t) {
            acc[t].x += __shfl_xor(acc[t].x, d);
            acc[t].y += __shfl_xor(acc[t].y, d);
        }
    // epilogue: lanes within each 4-group hold f-pair (2j, 2j+1)
    float w0 = sw[2 * j], w1 = sw[2 * j + 1], bb0 = sb[2 * j], bb1 = sb[2 * j + 1];
#pragma unroll
    for (int t = 0; t < 16; ++t) {
        int node = k * BSZ + t;
        float di = dinv[node];
        float2 gs = *(const float2*)(g1h + node * 8 + j * 2);
        float v0 = fmaxf(di * (acc[t].x + gs.x) + bb0, 0.f);
        float v1 = fmaxf(di * (acc[t].y + gs.y) + bb1, 0.f);
        float part = fmaf(v1, w1, v0 * w0);
        part += __shfl_xor(part, 1);
        part += __shfl_xor(part, 2);
        if (lane == 0) {
            if (HALF == 0) outv[node] = part;
            else           outv[node] = di * (h2a[node] + part);
        }
    }
}

// layer-2 aggregate (register) + finalize
__global__ __launch_bounds__(256) void passF(const int* __restrict__ eb, const int* __restrict__ X,
                                             const float* __restrict__ gg, const float* __restrict__ dinv,
                                             const float* __restrict__ b2, float* __restrict__ out) {
    int w = threadIdx.x >> 6, lane = threadIdx.x & 63;
    int k = blockIdx.x * 4 + w;
    if (k >= NBKT) return;
    int s = X[k], e = (k + 1 < NBKT) ? X[k + 1] : NE;
    int m4 = (lane & 3) * 4;
    float acc[4] = {0.f, 0.f, 0.f, 0.f};
    int nIter = (e - s + 15) >> 4;
    int i = s + (lane >> 2);
    int p = (i < e) ? __builtin_nontemporal_load(&eb[i]) : -1;
    for (int it = 0; it < nIter; ++it) {
        int inext = i + 16;
        int pnext = (inext < e) ? __builtin_nontemporal_load(&eb[inext]) : -1;
        if (p >= 0) {
            int r = p & 0x1FFFF, slot = (p >> 17) & 15;
            float v = gg[r];
#pragma unroll
            for (int t = 0; t < 4; ++t) {
                float m = (slot == m4 + t) ? 1.f : 0.f;
                acc[t] = fmaf(m, v, acc[t]);
            }
        }
        p = pnext; i = inext;
    }
#pragma unroll
    for (int d = 4; d < 64; d <<= 1)
#pragma unroll
        for (int t = 0; t < 4; ++t) acc[t] += __shfl_xor(acc[t], d);
    if (lane < 4) {
        float b = b2[0];
#pragma unroll
        for (int t = 0; t < 4; ++t) {
            int node = k * BSZ + lane * 4 + t;
            out[node] = fmaxf(dinv[node] * (acc[t] + gg[node]) + b, 0.f);
        }
    }
}

// ============================ fallback path (global atomics) ============================

__global__ void fb_deg(const int* __restrict__ col, float* __restrict__ deg, int E) {
    int stride = gridDim.x * blockDim.x;
    for (int i = blockIdx.x * blockDim.x + threadIdx.x; i < E; i += stride)
        atomicAdd(&deg[col[i]], 1.0f);
}
__global__ void fb_dinv(float* __restrict__ d, int N) {
    int i = blockIdx.x * blockDim.x + threadIdx.x;
    if (i < N) d[i] = rsqrtf(d[i] + 1.0f);
}
__global__ void fb_h1p(const float* __restrict__ x, const float* __restrict__ W1, float* __restrict__ h1p, int N) {
    __shared__ float sW[144];
    if (threadIdx.x < 144) sW[threadIdx.x] = W1[threadIdx.x];
    __syncthreads();
    int i = blockIdx.x * blockDim.x + threadIdx.x;
    if (i >= N) return;
    float xi[9];
#pragma unroll
    for (int q = 0; q < 9; ++q) xi[q] = x[i * 9 + q];
#pragma unroll
    for (int ff = 0; ff < 16; ++ff) {
        float a = 0.f;
#pragma unroll
        for (int q = 0; q < 9; ++q) a = fmaf(xi[q], sW[q * 16 + ff], a);
        h1p[i * 16 + ff] = a;
    }
}
__global__ void fb_sc1(const int* __restrict__ row, const int* __restrict__ col, const float* __restrict__ dinv,
                       const float* __restrict__ h1p, float* __restrict__ agg1, long total) {
    long stride = (long)gridDim.x * blockDim.x;
    for (long t = (long)blockIdx.x * blockDim.x + threadIdx.x; t < total; t += stride) {
        int e = (int)(t >> 4), ff = (int)(t & 15);
        int r = row[e], c = col[e];
        atomicAdd(&agg1[c * 16 + ff], h1p[r * 16 + ff] * dinv[r] * dinv[c]);
    }
}
__global__ void fb_fin1(const float* __restrict__ agg1, const float* __restrict__ h1p, const float* __restrict__ dinv,
                        const float* __restrict__ b1, const float* __restrict__ W2, float* __restrict__ h2p, int N) {
    __shared__ float sW2[16], sb1[16];
    if (threadIdx.x < 16) { sW2[threadIdx.x] = W2[threadIdx.x]; sb1[threadIdx.x] = b1[threadIdx.x]; }
    __syncthreads();
    int i = blockIdx.x * blockDim.x + threadIdx.x;
    if (i >= N) return;
    float di = dinv[i], self = di * di, a = 0.f;
#pragma unroll
    for (int ff = 0; ff < 16; ++ff) {
        float v = agg1[i * 16 + ff] + h1p[i * 16 + ff] * self + sb1[ff];
        a = fmaf(fmaxf(v, 0.f), sW2[ff], a);
    }
    h2p[i] = a;
}
__global__ void fb_sc2(const int* __restrict__ row, const int* __restrict__ col, const float* __restrict__ dinv,
                       const float* __restrict__ h2p, float* __restrict__ out, int E) {
    int stride = gridDim.x * blockDim.x;
    for (int e = blockIdx.x * blockDim.x + threadIdx.x; e < E; e += stride) {
        int r = row[e], c = col[e];
        atomicAdd(&out[c], h2p[r] * dinv[r] * dinv[c]);
    }
}
__global__ void fb_fin2(float* __restrict__ out, const float* __restrict__ h2p, const float* __restrict__ dinv,
                        const float* __restrict__ b2, int N) {
    int i = blockIdx.x * blockDim.x + threadIdx.x;
    if (i < N) {
        float di = dinv[i];
        out[i] = fmaxf(out[i] + h2p[i] * di * di + b2[0], 0.f);
    }
}

// ============================ launcher ============================

extern "C" void kernel_launch(void* const* d_in, const int* in_sizes, int n_in,
                              void* d_out, int out_size, void* d_ws, size_t ws_size,
                              hipStream_t stream) {
    const float* x  = (const float*)d_in[0];
    const int*   ei = (const int*)d_in[1];
    const float* W1 = (const float*)d_in[2];
    const float* b1 = (const float*)d_in[3];
    const float* W2 = (const float*)d_in[4];
    const float* b2 = (const float*)d_in[5];
    float* out = (float*)d_out;
    const int* row = ei;
    const int* col = ei + NE;
    char* ws = (char*)d_ws;

    constexpr size_t OFF_EB = 0;                          // 25,600,000 B
    constexpr size_t OFF_X  = 25600000;                   // 6,600,000 B region (X = 6.4MB; g1a/g1b overlay at +32KB, valid after passB)
    constexpr size_t OFF_CT = OFF_X + 6600000;            // 4096 B
    constexpr size_t OFF_CB = OFF_CT + 4096;              // 4096 B
    constexpr size_t OFF_DI = OFF_CB + 4096;              // 400,000 B
    constexpr size_t OFF_H2 = OFF_DI + 400000;            // 400,000 B
    constexpr size_t OFF_GG = OFF_H2 + 400000;            // 400,000 B
    constexpr size_t WS_NEED = OFF_GG + 400000;           // ~33.4 MB

    if (ws_size >= WS_NEED) {
        int*   eb    = (int*)(ws + OFF_EB);
        int*   X     = (int*)(ws + OFF_X);
        int*   ctot  = (int*)(ws + OFF_CT);
        int*   cbase = (int*)(ws + OFF_CB);
        float* dinv  = (float*)(ws + OFF_DI);
        float* h2a   = (float*)(ws + OFF_H2);
        float* gg    = (float*)(ws + OFF_GG);
        // overlay: X's chunk-offset region (b>0) is dead after passB; bucket starts live at X[0..NBKT]
        float* g1a   = (float*)(ws + OFF_X + 32768);      // 3,200,000 B
        float* g1b   = (float*)(ws + OFF_X + 32768 + 3200000);  // 3,200,000 B (ends < 6.6MB region)

        histA<<<NB, 512, 0, stream>>>(col, X);
        scan1<<<NCH, 512, 0, stream>>>(X, ctot);
        scan2<<<1, 1024, 0, stream>>>(ctot, cbase);
        scan3<<<(TOTBINS + 255) / 256, 256, 0, stream>>>(X, cbase);
        passB<<<NMC * 4, 1024, 0, stream>>>(row, col, X, eb);
        int gridK = (NBKT + 3) / 4;   // 1563
        passC<<<gridK, 256, 0, stream>>>(eb, X, x, W1, dinv, g1a, g1b);
        passE<0><<<gridK, 256, 0, stream>>>(eb, X, g1a, dinv, b1, W2, nullptr, h2a);
        passE<1><<<gridK, 256, 0, stream>>>(eb, X, g1b, dinv, b1, W2, h2a, gg);
        passF<<<gridK, 256, 0, stream>>>(eb, X, gg, dinv, b2, out);
    } else {
        // fallback: global-atomic version (needs ~13.8 MB)
        float* dinv = (float*)(ws);
        float* h1p  = (float*)(ws + 524288);
        float* agg1 = (float*)(ws + 6924288);
        float* h2p  = (float*)(ws + 13324288);
        hipMemsetAsync(dinv, 0, NN * sizeof(float), stream);
        hipMemsetAsync(agg1, 0, NN * 16 * sizeof(float), stream);
        hipMemsetAsync(out, 0, NN * sizeof(float), stream);
        const int B = 256;
        int gridN = (NN + B - 1) / B;
        fb_deg<<<4096, B, 0, stream>>>(col, dinv, NE);
        fb_dinv<<<gridN, B, 0, stream>>>(dinv, NN);
        fb_h1p<<<gridN, B, 0, stream>>>(x, W1, h1p, NN);
        fb_sc1<<<8192, B, 0, stream>>>(row, col, dinv, h1p, agg1, (long)NE * 16);
        fb_fin1<<<gridN, B, 0, stream>>>(agg1, h1p, dinv, b1, W2, h2p, NN);
        fb_sc2<<<4096, B, 0, stream>>>(row, col, dinv, h2p, out, NE);
        fb_fin2<<<gridN, B, 0, stream>>>(out, h2p, dinv, b2, NN);
    }
}

// Round 7
// 492.053 us; speedup vs baseline: 1.0557x; 1.0557x over previous
//
#include <hip/hip_runtime.h>

#define NN 100000
#define NE 6400000
#define BSZ 16                    // nodes per bucket
#define NBKT 6250                 // NN/BSZ exactly
#define NB 256                    // sort chunks
#define CHUNK 25000               // NE/NB exactly
#define TOTBINS (NBKT * NB)       // 1,600,000
#define SC1 2048                  // elems per scan1 block
#define NCH ((TOTBINS + SC1 - 1) / SC1)   // 782

// ============================ fast path ============================

// X[b*NBKT + k] = count of edges in chunk b destined to bucket k
__global__ __launch_bounds__(512) void histA(const int* __restrict__ col, int* __restrict__ X) {
    __shared__ int h[NBKT];
    for (int i = threadIdx.x; i < NBKT; i += 512) h[i] = 0;
    __syncthreads();
    const int* c = col + blockIdx.x * CHUNK;
    for (int i = threadIdx.x; i < CHUNK; i += 512)
        atomicAdd(&h[__builtin_nontemporal_load(&c[i]) >> 4], 1);
    __syncthreads();
    int* o = X + blockIdx.x * NBKT;
    for (int i = threadIdx.x; i < NBKT; i += 512) o[i] = h[i];
}

// in-place exclusive scan over logical order idx = k*NB + b (storage X[b*NBKT+k])
__global__ __launch_bounds__(512) void scan1(int* __restrict__ X, int* __restrict__ ctot) {
    __shared__ int buf[SC1];
    __shared__ int ts[512];
    int base = blockIdx.x * SC1;
    for (int j = threadIdx.x; j < SC1; j += 512) {
        int idx = base + j; int v = 0;
        if (idx < TOTBINS) { int k = idx >> 8, b = idx & 255; v = X[b * NBKT + k]; }
        buf[j] = v;
    }
    __syncthreads();
    int j0 = threadIdx.x * 4;
    int a0 = buf[j0], a1 = buf[j0 + 1], a2 = buf[j0 + 2], a3 = buf[j0 + 3];
    int s = a0 + a1 + a2 + a3;
    ts[threadIdx.x] = s;
    __syncthreads();
    for (int off = 1; off < 512; off <<= 1) {
        int u = (threadIdx.x >= off) ? ts[threadIdx.x - off] : 0;
        __syncthreads();
        ts[threadIdx.x] += u;
        __syncthreads();
    }
    int e0 = ts[threadIdx.x] - s;
    int ev[4] = {e0, e0 + a0, e0 + a0 + a1, e0 + a0 + a1 + a2};
#pragma unroll
    for (int t = 0; t < 4; ++t) {
        int idx = base + j0 + t;
        if (idx < TOTBINS) { int k = idx >> 8, b = idx & 255; X[b * NBKT + k] = ev[t]; }
    }
    if (threadIdx.x == 511) ctot[blockIdx.x] = ts[511];
}

__global__ void scan2(const int* __restrict__ ctot, int* __restrict__ cbase) {
    __shared__ int ts[1024];
    int t = threadIdx.x;
    int orig = (t < NCH) ? ctot[t] : 0;
    ts[t] = orig;
    __syncthreads();
    for (int off = 1; off < 1024; off <<= 1) {
        int u = (t >= off) ? ts[t - off] : 0;
        __syncthreads();
        ts[t] += u;
        __syncthreads();
    }
    if (t < NCH) cbase[t] = ts[t] - orig;
}

__global__ __launch_bounds__(256) void scan3(int* __restrict__ X, const int* __restrict__ cbase) {
    int m = blockIdx.x * 256 + threadIdx.x;
    if (m >= TOTBINS) return;
    int b = m / NBKT;
    int k = m - b * NBKT;
    int idx = (k << 8) | b;
    X[m] += cbase[idx >> 11];     // SC1 = 2048
}

// scatter edges into bucket-sorted eb; pack (slot<<17 | row).
// chunk index is XCD-clustered: chunks 0..31 on XCD0, 32..63 on XCD1, ...
// so all writers of a bucket's adjacent runs share an XCD L2 -> partial
// lines merge before writeback (kills the 7x write amplification).
__global__ __launch_bounds__(512) void passB(const int* __restrict__ row, const int* __restrict__ col,
                                             const int* __restrict__ X, int* __restrict__ eb) {
    __shared__ int cur[NBKT];
    int b = ((blockIdx.x & 7) << 5) | (blockIdx.x >> 3);   // XCD-clustered chunk id
    const int* st = X + b * NBKT;
    for (int i = threadIdx.x; i < NBKT; i += 512) cur[i] = st[i];
    __syncthreads();
    const int* c = col + b * CHUNK;
    const int* r = row + b * CHUNK;
    for (int i = threadIdx.x; i < CHUNK; i += 512) {
        int cc = __builtin_nontemporal_load(&c[i]);
        int rr = __builtin_nontemporal_load(&r[i]);
        int pos = atomicAdd(&cur[cc >> 4], 1);
        eb[pos] = rr | ((cc & 15) << 17);
    }
}

// degree (register cndmask count) -> dinv, fused with g1a/g1b = dinv * (x@W1) halves
__global__ __launch_bounds__(256) void passC(const int* __restrict__ eb, const int* __restrict__ X,
                                             const float* __restrict__ x, const float* __restrict__ W1,
                                             float* __restrict__ dinv, float* __restrict__ g1a,
                                             float* __restrict__ g1b) {
    __shared__ float sW[144];
    __shared__ int cdeg[4][16];
    for (int i = threadIdx.x; i < 144; i += 256) sW[i] = W1[i];
    int w = threadIdx.x >> 6, lane = threadIdx.x & 63;
    int k = blockIdx.x * 4 + w;
    if (k < NBKT) {
        int s = X[k], e = (k + 1 < NBKT) ? X[k + 1] : NE;
        int m4 = (lane & 3) * 4;
        int deg4[4] = {0, 0, 0, 0};
        for (int i = s + (lane >> 2); i < e; i += 16) {
            int p = __builtin_nontemporal_load(&eb[i]);
            int slot = (p >> 17) & 15;
#pragma unroll
            for (int t = 0; t < 4; ++t) deg4[t] += (slot == m4 + t) ? 1 : 0;
        }
#pragma unroll
        for (int d = 4; d < 64; d <<= 1)
#pragma unroll
            for (int t = 0; t < 4; ++t) deg4[t] += __shfl_xor(deg4[t], d);
        if (lane < 4)
#pragma unroll
            for (int t = 0; t < 4; ++t) cdeg[w][lane * 4 + t] = deg4[t];
    }
    __syncthreads();
    if (k < NBKT) {
        int node0 = k * BSZ;
        if (lane < 16) dinv[node0 + lane] = rsqrtf((float)cdeg[w][lane] + 1.f);
        int nd = lane >> 2, fq = lane & 3;
        int node = node0 + nd;
        float di = rsqrtf((float)cdeg[w][nd] + 1.f);
        float xr[9];
#pragma unroll
        for (int q = 0; q < 9; ++q) xr[q] = x[node * 9 + q];
        float4 o;
        float* op = &o.x;
#pragma unroll
        for (int j = 0; j < 4; ++j) {
            int f = fq * 4 + j;
            float a = 0.f;
#pragma unroll
            for (int q = 0; q < 9; ++q) a = fmaf(xr[q], sW[q * 16 + f], a);
            op[j] = a * di;
        }
        if (fq < 2) *(float4*)(g1a + node * 8 + fq * 4) = o;
        else        *(float4*)(g1b + node * 8 + (fq - 2) * 4) = o;
    }
}

// half of layer-1: register accumulate + relu + partial layer-2 dot.
// HALF=0: outv[n] = partial h2 (features 0-7). HALF=1: outv[n] = gg[n] = dinv*(h2a+partial).
template <int HALF>
__global__ __launch_bounds__(256) void passE(const int* __restrict__ eb, const int* __restrict__ X,
                                             const float* __restrict__ g1h, const float* __restrict__ dinv,
                                             const float* __restrict__ b1, const float* __restrict__ W2,
                                             const float* __restrict__ h2a, float* __restrict__ outv) {
    __shared__ float sb[8], sw[8];
    if (threadIdx.x < 8) {
        sb[threadIdx.x] = b1[HALF * 8 + threadIdx.x];
        sw[threadIdx.x] = W2[HALF * 8 + threadIdx.x];
    }
    __syncthreads();
    int w = threadIdx.x >> 6, lane = threadIdx.x & 63;
    int k = blockIdx.x * 4 + w;
    if (k >= NBKT) return;
    int s = X[k], e = (k + 1 < NBKT) ? X[k + 1] : NE;
    int j = lane & 3, ego = lane >> 2;
    float2 acc[16];
#pragma unroll
    for (int t = 0; t < 16; ++t) { acc[t].x = 0.f; acc[t].y = 0.f; }
    int nIter = (e - s + 15) >> 4;
    int i = s + ego;
    int p = (i < e) ? __builtin_nontemporal_load(&eb[i]) : -1;
    for (int it = 0; it < nIter; ++it) {
        int inext = i + 16;
        int pnext = (inext < e) ? __builtin_nontemporal_load(&eb[inext]) : -1;
        if (p >= 0) {
            int r = p & 0x1FFFF, slot = (p >> 17) & 15;
            float2 g = *(const float2*)(g1h + r * 8 + j * 2);
#pragma unroll
            for (int t = 0; t < 16; ++t) {
                float m = (slot == t) ? 1.f : 0.f;
                acc[t].x = fmaf(m, g.x, acc[t].x);
                acc[t].y = fmaf(m, g.y, acc[t].y);
            }
        }
        p = pnext; i = inext;
    }
#pragma unroll
    for (int d = 4; d < 64; d <<= 1)
#pragma unroll
        for (int t = 0; t < 16; ++t) {
            acc[t].x += __shfl_xor(acc[t].x, d);
            acc[t].y += __shfl_xor(acc[t].y, d);
        }
    // epilogue: lanes within each 4-group hold f-pair (2j, 2j+1)
    float w0 = sw[2 * j], w1 = sw[2 * j + 1], bb0 = sb[2 * j], bb1 = sb[2 * j + 1];
#pragma unroll
    for (int t = 0; t < 16; ++t) {
        int node = k * BSZ + t;
        float di = dinv[node];
        float2 gs = *(const float2*)(g1h + node * 8 + j * 2);
        float v0 = fmaxf(di * (acc[t].x + gs.x) + bb0, 0.f);
        float v1 = fmaxf(di * (acc[t].y + gs.y) + bb1, 0.f);
        float part = fmaf(v1, w1, v0 * w0);
        part += __shfl_xor(part, 1);
        part += __shfl_xor(part, 2);
        if (lane == 0) {
            if (HALF == 0) outv[node] = part;
            else           outv[node] = di * (h2a[node] + part);
        }
    }
}

// layer-2 aggregate (register) + finalize
__global__ __launch_bounds__(256) void passF(const int* __restrict__ eb, const int* __restrict__ X,
                                             const float* __restrict__ gg, const float* __restrict__ dinv,
                                             const float* __restrict__ b2, float* __restrict__ out) {
    int w = threadIdx.x >> 6, lane = threadIdx.x & 63;
    int k = blockIdx.x * 4 + w;
    if (k >= NBKT) return;
    int s = X[k], e = (k + 1 < NBKT) ? X[k + 1] : NE;
    int m4 = (lane & 3) * 4;
    float acc[4] = {0.f, 0.f, 0.f, 0.f};
    int nIter = (e - s + 15) >> 4;
    int i = s + (lane >> 2);
    int p = (i < e) ? __builtin_nontemporal_load(&eb[i]) : -1;
    for (int it = 0; it < nIter; ++it) {
        int inext = i + 16;
        int pnext = (inext < e) ? __builtin_nontemporal_load(&eb[inext]) : -1;
        if (p >= 0) {
            int r = p & 0x1FFFF, slot = (p >> 17) & 15;
            float v = gg[r];
#pragma unroll
            for (int t = 0; t < 4; ++t) {
                float m = (slot == m4 + t) ? 1.f : 0.f;
                acc[t] = fmaf(m, v, acc[t]);
            }
        }
        p = pnext; i = inext;
    }
#pragma unroll
    for (int d = 4; d < 64; d <<= 1)
#pragma unroll
        for (int t = 0; t < 4; ++t) acc[t] += __shfl_xor(acc[t], d);
    if (lane < 4) {
        float b = b2[0];
#pragma unroll
        for (int t = 0; t < 4; ++t) {
            int node = k * BSZ + lane * 4 + t;
            out[node] = fmaxf(dinv[node] * (acc[t] + gg[node]) + b, 0.f);
        }
    }
}

// ============================ fallback path (global atomics) ============================

__global__ void fb_deg(const int* __restrict__ col, float* __restrict__ deg, int E) {
    int stride = gridDim.x * blockDim.x;
    for (int i = blockIdx.x * blockDim.x + threadIdx.x; i < E; i += stride)
        atomicAdd(&deg[col[i]], 1.0f);
}
__global__ void fb_dinv(float* __restrict__ d, int N) {
    int i = blockIdx.x * blockDim.x + threadIdx.x;
    if (i < N) d[i] = rsqrtf(d[i] + 1.0f);
}
__global__ void fb_h1p(const float* __restrict__ x, const float* __restrict__ W1, float* __restrict__ h1p, int N) {
    __shared__ float sW[144];
    if (threadIdx.x < 144) sW[threadIdx.x] = W1[threadIdx.x];
    __syncthreads();
    int i = blockIdx.x * blockDim.x + threadIdx.x;
    if (i >= N) return;
    float xi[9];
#pragma unroll
    for (int q = 0; q < 9; ++q) xi[q] = x[i * 9 + q];
#pragma unroll
    for (int ff = 0; ff < 16; ++ff) {
        float a = 0.f;
#pragma unroll
        for (int q = 0; q < 9; ++q) a = fmaf(xi[q], sW[q * 16 + ff], a);
        h1p[i * 16 + ff] = a;
    }
}
__global__ void fb_sc1(const int* __restrict__ row, const int* __restrict__ col, const float* __restrict__ dinv,
                       const float* __restrict__ h1p, float* __restrict__ agg1, long total) {
    long stride = (long)gridDim.x * blockDim.x;
    for (long t = (long)blockIdx.x * blockDim.x + threadIdx.x; t < total; t += stride) {
        int e = (int)(t >> 4), ff = (int)(t & 15);
        int r = row[e], c = col[e];
        atomicAdd(&agg1[c * 16 + ff], h1p[r * 16 + ff] * dinv[r] * dinv[c]);
    }
}
__global__ void fb_fin1(const float* __restrict__ agg1, const float* __restrict__ h1p, const float* __restrict__ dinv,
                        const float* __restrict__ b1, const float* __restrict__ W2, float* __restrict__ h2p, int N) {
    __shared__ float sW2[16], sb1[16];
    if (threadIdx.x < 16) { sW2[threadIdx.x] = W2[threadIdx.x]; sb1[threadIdx.x] = b1[threadIdx.x]; }
    __syncthreads();
    int i = blockIdx.x * blockDim.x + threadIdx.x;
    if (i >= N) return;
    float di = dinv[i], self = di * di, a = 0.f;
#pragma unroll
    for (int ff = 0; ff < 16; ++ff) {
        float v = agg1[i * 16 + ff] + h1p[i * 16 + ff] * self + sb1[ff];
        a = fmaf(fmaxf(v, 0.f), sW2[ff], a);
    }
    h2p[i] = a;
}
__global__ void fb_sc2(const int* __restrict__ row, const int* __restrict__ col, const float* __restrict__ dinv,
                       const float* __restrict__ h2p, float* __restrict__ out, int E) {
    int stride = gridDim.x * blockDim.x;
    for (int e = blockIdx.x * blockDim.x + threadIdx.x; e < E; e += stride) {
        int r = row[e], c = col[e];
        atomicAdd(&out[c], h2p[r] * dinv[r] * dinv[c]);
    }
}
__global__ void fb_fin2(float* __restrict__ out, const float* __restrict__ h2p, const float* __restrict__ dinv,
                        const float* __restrict__ b2, int N) {
    int i = blockIdx.x * blockDim.x + threadIdx.x;
    if (i < N) {
        float di = dinv[i];
        out[i] = fmaxf(out[i] + h2p[i] * di * di + b2[0], 0.f);
    }
}

// ============================ launcher ============================

extern "C" void kernel_launch(void* const* d_in, const int* in_sizes, int n_in,
                              void* d_out, int out_size, void* d_ws, size_t ws_size,
                              hipStream_t stream) {
    const float* x  = (const float*)d_in[0];
    const int*   ei = (const int*)d_in[1];
    const float* W1 = (const float*)d_in[2];
    const float* b1 = (const float*)d_in[3];
    const float* W2 = (const float*)d_in[4];
    const float* b2 = (const float*)d_in[5];
    float* out = (float*)d_out;
    const int* row = ei;
    const int* col = ei + NE;
    char* ws = (char*)d_ws;

    constexpr size_t OFF_EB = 0;                          // 25,600,000 B
    constexpr size_t OFF_X  = 25600000;                   // 6,600,000 B region (X = 6.4MB; g1a/g1b overlay at +32KB, valid after passB)
    constexpr size_t OFF_CT = OFF_X + 6600000;            // 4096 B
    constexpr size_t OFF_CB = OFF_CT + 4096;              // 4096 B
    constexpr size_t OFF_DI = OFF_CB + 4096;              // 400,000 B
    constexpr size_t OFF_H2 = OFF_DI + 400000;            // 400,000 B
    constexpr size_t OFF_GG = OFF_H2 + 400000;            // 400,000 B
    constexpr size_t WS_NEED = OFF_GG + 400000;           // ~33.4 MB

    if (ws_size >= WS_NEED) {
        int*   eb    = (int*)(ws + OFF_EB);
        int*   X     = (int*)(ws + OFF_X);
        int*   ctot  = (int*)(ws + OFF_CT);
        int*   cbase = (int*)(ws + OFF_CB);
        float* dinv  = (float*)(ws + OFF_DI);
        float* h2a   = (float*)(ws + OFF_H2);
        float* gg    = (float*)(ws + OFF_GG);
        // overlay: X's chunk-offset region (b>0) is dead after passB; bucket starts live at X[0..NBKT]
        float* g1a   = (float*)(ws + OFF_X + 32768);      // 3,200,000 B
        float* g1b   = (float*)(ws + OFF_X + 32768 + 3200000);  // 3,200,000 B (ends < 6.6MB region)

        histA<<<NB, 512, 0, stream>>>(col, X);
        scan1<<<NCH, 512, 0, stream>>>(X, ctot);
        scan2<<<1, 1024, 0, stream>>>(ctot, cbase);
        scan3<<<(TOTBINS + 255) / 256, 256, 0, stream>>>(X, cbase);
        passB<<<NB, 512, 0, stream>>>(row, col, X, eb);
        int gridK = (NBKT + 3) / 4;   // 1563
        passC<<<gridK, 256, 0, stream>>>(eb, X, x, W1, dinv, g1a, g1b);
        passE<0><<<gridK, 256, 0, stream>>>(eb, X, g1a, dinv, b1, W2, nullptr, h2a);
        passE<1><<<gridK, 256, 0, stream>>>(eb, X, g1b, dinv, b1, W2, h2a, gg);
        passF<<<gridK, 256, 0, stream>>>(eb, X, gg, dinv, b2, out);
    } else {
        // fallback: global-atomic version (needs ~13.8 MB)
        float* dinv = (float*)(ws);
        float* h1p  = (float*)(ws + 524288);
        float* agg1 = (float*)(ws + 6924288);
        float* h2p  = (float*)(ws + 13324288);
        hipMemsetAsync(dinv, 0, NN * sizeof(float), stream);
        hipMemsetAsync(agg1, 0, NN * 16 * sizeof(float), stream);
        hipMemsetAsync(out, 0, NN * sizeof(float), stream);
        const int B = 256;
        int gridN = (NN + B - 1) / B;
        fb_deg<<<4096, B, 0, stream>>>(col, dinv, NE);
        fb_dinv<<<gridN, B, 0, stream>>>(dinv, NN);
        fb_h1p<<<gridN, B, 0, stream>>>(x, W1, h1p, NN);
        fb_sc1<<<8192, B, 0, stream>>>(row, col, dinv, h1p, agg1, (long)NE * 16);
        fb_fin1<<<gridN, B, 0, stream>>>(agg1, h1p, dinv, b1, W2, h2p, NN);
        fb_sc2<<<4096, B, 0, stream>>>(row, col, dinv, h2p, out, NE);
        fb_fin2<<<gridN, B, 0, stream>>>(out, h2p, dinv, b2, NN);
    }
}

// Round 8
// 295.417 us; speedup vs baseline: 1.7584x; 1.6656x over previous
//
#include <hip/hip_runtime.h>

#define NN 100000
#define NE 6400000
#define BSZ 16                    // nodes per bucket (NN = NBKT*BSZ exactly)
#define NBKT 6250
#define NB 256                    // sort chunks
#define CHUNK 25000               // NE/NB exactly
#define TOTBINS (NBKT * NB)       // 1,600,000
#define SC1 2048                  // elems per scan1 block
#define NCH ((TOTBINS + SC1 - 1) / SC1)   // 782

// ============================ fast path ============================

// X[b*NBKT + k] = count of edges in chunk b destined to bucket k
__global__ __launch_bounds__(512) void histA(const int* __restrict__ col, int* __restrict__ X) {
    __shared__ int h[NBKT];
    for (int i = threadIdx.x; i < NBKT; i += 512) h[i] = 0;
    __syncthreads();
    const int* c = col + blockIdx.x * CHUNK;
    for (int i = threadIdx.x; i < CHUNK; i += 512)
        atomicAdd(&h[c[i] >> 4], 1);
    __syncthreads();
    int* o = X + blockIdx.x * NBKT;
    for (int i = threadIdx.x; i < NBKT; i += 512) o[i] = h[i];
}

// in-place exclusive scan over logical order idx = k*NB + b (storage X[b*NBKT+k])
__global__ __launch_bounds__(512) void scan1(int* __restrict__ X, int* __restrict__ ctot) {
    __shared__ int buf[SC1];
    __shared__ int ts[512];
    int base = blockIdx.x * SC1;
    for (int j = threadIdx.x; j < SC1; j += 512) {
        int idx = base + j; int v = 0;
        if (idx < TOTBINS) { int k = idx >> 8, b = idx & 255; v = X[b * NBKT + k]; }
        buf[j] = v;
    }
    __syncthreads();
    int j0 = threadIdx.x * 4;
    int a0 = buf[j0], a1 = buf[j0 + 1], a2 = buf[j0 + 2], a3 = buf[j0 + 3];
    int s = a0 + a1 + a2 + a3;
    ts[threadIdx.x] = s;
    __syncthreads();
    for (int off = 1; off < 512; off <<= 1) {
        int u = (threadIdx.x >= off) ? ts[threadIdx.x - off] : 0;
        __syncthreads();
        ts[threadIdx.x] += u;
        __syncthreads();
    }
    int e0 = ts[threadIdx.x] - s;
    int ev[4] = {e0, e0 + a0, e0 + a0 + a1, e0 + a0 + a1 + a2};
#pragma unroll
    for (int t = 0; t < 4; ++t) {
        int idx = base + j0 + t;
        if (idx < TOTBINS) { int k = idx >> 8, b = idx & 255; X[b * NBKT + k] = ev[t]; }
    }
    if (threadIdx.x == 511) ctot[blockIdx.x] = ts[511];
}

__global__ void scan2(const int* __restrict__ ctot, int* __restrict__ cbase) {
    __shared__ int ts[1024];
    int t = threadIdx.x;
    int orig = (t < NCH) ? ctot[t] : 0;
    ts[t] = orig;
    __syncthreads();
    for (int off = 1; off < 1024; off <<= 1) {
        int u = (t >= off) ? ts[t - off] : 0;
        __syncthreads();
        ts[t] += u;
        __syncthreads();
    }
    if (t < NCH) cbase[t] = ts[t] - orig;
}

__global__ __launch_bounds__(256) void scan3(int* __restrict__ X, const int* __restrict__ cbase) {
    int m = blockIdx.x * 256 + threadIdx.x;
    if (m >= TOTBINS) return;
    int b = m / NBKT;
    int k = m - b * NBKT;
    int idx = (k << 8) | b;
    X[m] += cbase[idx >> 11];     // SC1 = 2048
}

// scatter edges into bucket-sorted eb; pack (slot<<17 | row).
// XCD-clustered chunk order: all writers of a bucket's adjacent runs share an
// XCD L2 -> partial lines merge before writeback.
__global__ __launch_bounds__(512) void passB(const int* __restrict__ row, const int* __restrict__ col,
                                             const int* __restrict__ X, int* __restrict__ eb) {
    __shared__ int cur[NBKT];
    int b = ((blockIdx.x & 7) << 5) | (blockIdx.x >> 3);   // XCD-clustered chunk id
    const int* st = X + b * NBKT;
    for (int i = threadIdx.x; i < NBKT; i += 512) cur[i] = st[i];
    __syncthreads();
    const int* c = col + b * CHUNK;
    const int* r = row + b * CHUNK;
    for (int i = threadIdx.x; i < CHUNK; i += 512) {
        int cc = c[i];
        int pos = atomicAdd(&cur[cc >> 4], 1);
        eb[pos] = r[i] | ((cc & 15) << 17);
    }
}

// degree (register count, int4 edge loads) -> dinv, fused with g1 = dinv*(x@W1)
__global__ __launch_bounds__(256) void passC(const int* __restrict__ eb, const int* __restrict__ X,
                                             const float* __restrict__ x, const float* __restrict__ W1,
                                             float* __restrict__ dinv, float* __restrict__ g1) {
    __shared__ float sW[144];
    __shared__ int cdeg[4][16];
    for (int i = threadIdx.x; i < 144; i += 256) sW[i] = W1[i];
    int w = threadIdx.x >> 6, lane = threadIdx.x & 63;
    int k = blockIdx.x * 4 + w;
    if (k < NBKT) {
        int s = X[k], e = (k + 1 < NBKT) ? X[k + 1] : NE;
        int g = lane >> 2;            // 16 groups, int4 each -> 64 edges/iter
        int m4 = (lane & 3) * 4;
        int base = s & ~3;
        int total4 = (e - base + 3) >> 2;
        int nIt = (total4 + 15) >> 4;
        const int4* ebv = (const int4*)(eb + base);
        int deg4[4] = {0, 0, 0, 0};
        int4 pk = (g < total4) ? ebv[g] : make_int4(0, 0, 0, 0);
        for (int it = 0; it < nIt; ++it) {
            int i4n = (it + 1) * 16 + g;
            int4 pkn = (i4n < total4) ? ebv[i4n] : make_int4(0, 0, 0, 0);
            int ibase = base + (it * 16 + g) * 4;
            int pq[4] = {pk.x, pk.y, pk.z, pk.w};
#pragma unroll
            for (int q = 0; q < 4; ++q) {
                int idx = ibase + q;
                int sl = (idx >= s && idx < e) ? ((pq[q] >> 17) & 15) : 16;
#pragma unroll
                for (int t = 0; t < 4; ++t) deg4[t] += (sl == m4 + t) ? 1 : 0;
            }
            pk = pkn;
        }
#pragma unroll
        for (int d = 4; d < 64; d <<= 1)
#pragma unroll
            for (int t = 0; t < 4; ++t) deg4[t] += __shfl_xor(deg4[t], d);
        if (lane < 4)
#pragma unroll
            for (int t = 0; t < 4; ++t) cdeg[w][lane * 4 + t] = deg4[t];
    }
    __syncthreads();
    if (k < NBKT) {
        int node0 = k * BSZ;
        if (lane < 16) dinv[node0 + lane] = rsqrtf((float)cdeg[w][lane] + 1.f);
        int nd = lane >> 2, fq = lane & 3;
        int node = node0 + nd;
        float di = rsqrtf((float)cdeg[w][nd] + 1.f);
        float xr[9];
#pragma unroll
        for (int q = 0; q < 9; ++q) xr[q] = x[node * 9 + q];
        float4 o;
        float* op = &o.x;
#pragma unroll
        for (int j = 0; j < 4; ++j) {
            int f = fq * 4 + j;
            float a = 0.f;
#pragma unroll
            for (int q = 0; q < 9; ++q) a = fmaf(xr[q], sW[q * 16 + f], a);
            op[j] = a * di;
        }
        *(float4*)(g1 + (node << 4) + (fq << 2)) = o;
    }
}

// fused layer-1 aggregate over ALL 16 features (one eb pass):
// gg[c] = dinv[c] * sum_f relu(dinv[c]*(sum_r g1[r][f] + g1[c][f]) + b1[f]) * W2[f]
// 8 lanes per edge (feature-pair fp), 8 edge-groups, int4 eb loads (32 edges/iter).
__global__ __launch_bounds__(256) void passE(const int* __restrict__ eb, const int* __restrict__ X,
                                             const float* __restrict__ g1, const float* __restrict__ dinv,
                                             const float* __restrict__ b1, const float* __restrict__ W2,
                                             float* __restrict__ gg) {
    __shared__ float sb1[16], sW2[16];
    if (threadIdx.x < 16) { sb1[threadIdx.x] = b1[threadIdx.x]; sW2[threadIdx.x] = W2[threadIdx.x]; }
    __syncthreads();
    int w = threadIdx.x >> 6, lane = threadIdx.x & 63;
    int k = blockIdx.x * 4 + w;
    if (k >= NBKT) return;
    int s = X[k], e = (k + 1 < NBKT) ? X[k + 1] : NE;
    int g  = lane >> 3;           // edge group 0..7
    int fp = lane & 7;            // feature pair 0..7
    float2 acc[16];
#pragma unroll
    for (int t = 0; t < 16; ++t) { acc[t].x = 0.f; acc[t].y = 0.f; }
    int base = s & ~3;
    int total4 = (e - base + 3) >> 2;
    int nIt = (total4 + 7) >> 3;
    const int4* ebv = (const int4*)(eb + base);
    int4 pk = (g < total4) ? ebv[g] : make_int4(0, 0, 0, 0);
    for (int it = 0; it < nIt; ++it) {
        int i4n = (it + 1) * 8 + g;
        int4 pkn = (i4n < total4) ? ebv[i4n] : make_int4(0, 0, 0, 0);
        int ibase = base + (it * 8 + g) * 4;
        int pq[4] = {pk.x, pk.y, pk.z, pk.w};
        int sl[4];
        float2 gv[4];
#pragma unroll
        for (int q = 0; q < 4; ++q) {
            int idx = ibase + q;
            int r = pq[q] & 0x1FFFF;
            sl[q] = (idx >= s && idx < e) ? ((pq[q] >> 17) & 15) : 16;
            gv[q] = *(const float2*)(g1 + (r << 4) + (fp << 1));
        }
#pragma unroll
        for (int q = 0; q < 4; ++q)
#pragma unroll
            for (int t = 0; t < 16; ++t) {
                float m = (sl[q] == t) ? 1.f : 0.f;
                acc[t].x = fmaf(m, gv[q].x, acc[t].x);
                acc[t].y = fmaf(m, gv[q].y, acc[t].y);
            }
        pk = pkn;
    }
    // reduce across the 8 edge-groups (lanes with same fp)
#pragma unroll
    for (int d = 8; d < 64; d <<= 1)
#pragma unroll
        for (int t = 0; t < 16; ++t) {
            acc[t].x += __shfl_xor(acc[t].x, d);
            acc[t].y += __shfl_xor(acc[t].y, d);
        }
    float w0 = sW2[2 * fp], w1 = sW2[2 * fp + 1];
    float bb0 = sb1[2 * fp], bb1 = sb1[2 * fp + 1];
#pragma unroll
    for (int t = 0; t < 16; ++t) {
        int node = k * BSZ + t;
        float di = dinv[node];
        float2 gs = *(const float2*)(g1 + (node << 4) + (fp << 1));
        float v0 = fmaxf(di * (acc[t].x + gs.x) + bb0, 0.f);
        float v1 = fmaxf(di * (acc[t].y + gs.y) + bb1, 0.f);
        float part = fmaf(v1, w1, v0 * w0);
        part += __shfl_xor(part, 1);
        part += __shfl_xor(part, 2);
        part += __shfl_xor(part, 4);
        if (lane == 0) gg[node] = di * part;
    }
}

// layer-2 aggregate (register, int4 edge loads) + finalize
__global__ __launch_bounds__(256) void passF(const int* __restrict__ eb, const int* __restrict__ X,
                                             const float* __restrict__ gg, const float* __restrict__ dinv,
                                             const float* __restrict__ b2, float* __restrict__ out) {
    int w = threadIdx.x >> 6, lane = threadIdx.x & 63;
    int k = blockIdx.x * 4 + w;
    if (k >= NBKT) return;
    int s = X[k], e = (k + 1 < NBKT) ? X[k + 1] : NE;
    int g = lane >> 2;            // 16 groups, int4 each -> 64 edges/iter
    int m4 = (lane & 3) * 4;
    float acc[4] = {0.f, 0.f, 0.f, 0.f};
    int base = s & ~3;
    int total4 = (e - base + 3) >> 2;
    int nIt = (total4 + 15) >> 4;
    const int4* ebv = (const int4*)(eb + base);
    int4 pk = (g < total4) ? ebv[g] : make_int4(0, 0, 0, 0);
    for (int it = 0; it < nIt; ++it) {
        int i4n = (it + 1) * 16 + g;
        int4 pkn = (i4n < total4) ? ebv[i4n] : make_int4(0, 0, 0, 0);
        int ibase = base + (it * 16 + g) * 4;
        int pq[4] = {pk.x, pk.y, pk.z, pk.w};
        int sl[4];
        float gv[4];
#pragma unroll
        for (int q = 0; q < 4; ++q) {
            int idx = ibase + q;
            int r = pq[q] & 0x1FFFF;
            sl[q] = (idx >= s && idx < e) ? ((pq[q] >> 17) & 15) : 16;
            gv[q] = gg[r];
        }
#pragma unroll
        for (int q = 0; q < 4; ++q)
#pragma unroll
            for (int t = 0; t < 4; ++t) {
                float m = (sl[q] == m4 + t) ? 1.f : 0.f;
                acc[t] = fmaf(m, gv[q], acc[t]);
            }
        pk = pkn;
    }
#pragma unroll
    for (int d = 4; d < 64; d <<= 1)
#pragma unroll
        for (int t = 0; t < 4; ++t) acc[t] += __shfl_xor(acc[t], d);
    if (lane < 4) {
        float b = b2[0];
#pragma unroll
        for (int t = 0; t < 4; ++t) {
            int node = k * BSZ + lane * 4 + t;
            out[node] = fmaxf(dinv[node] * (acc[t] + gg[node]) + b, 0.f);
        }
    }
}

// ============================ fallback path (global atomics) ============================

__global__ void fb_deg(const int* __restrict__ col, float* __restrict__ deg, int E) {
    int stride = gridDim.x * blockDim.x;
    for (int i = blockIdx.x * blockDim.x + threadIdx.x; i < E; i += stride)
        atomicAdd(&deg[col[i]], 1.0f);
}
__global__ void fb_dinv(float* __restrict__ d, int N) {
    int i = blockIdx.x * blockDim.x + threadIdx.x;
    if (i < N) d[i] = rsqrtf(d[i] + 1.0f);
}
__global__ void fb_h1p(const float* __restrict__ x, const float* __restrict__ W1, float* __restrict__ h1p, int N) {
    __shared__ float sW[144];
    if (threadIdx.x < 144) sW[threadIdx.x] = W1[threadIdx.x];
    __syncthreads();
    int i = blockIdx.x * blockDim.x + threadIdx.x;
    if (i >= N) return;
    float xi[9];
#pragma unroll
    for (int q = 0; q < 9; ++q) xi[q] = x[i * 9 + q];
#pragma unroll
    for (int ff = 0; ff < 16; ++ff) {
        float a = 0.f;
#pragma unroll
        for (int q = 0; q < 9; ++q) a = fmaf(xi[q], sW[q * 16 + ff], a);
        h1p[i * 16 + ff] = a;
    }
}
__global__ void fb_sc1(const int* __restrict__ row, const int* __restrict__ col, const float* __restrict__ dinv,
                       const float* __restrict__ h1p, float* __restrict__ agg1, long total) {
    long stride = (long)gridDim.x * blockDim.x;
    for (long t = (long)blockIdx.x * blockDim.x + threadIdx.x; t < total; t += stride) {
        int e = (int)(t >> 4), ff = (int)(t & 15);
        int r = row[e], c = col[e];
        atomicAdd(&agg1[c * 16 + ff], h1p[r * 16 + ff] * dinv[r] * dinv[c]);
    }
}
__global__ void fb_fin1(const float* __restrict__ agg1, const float* __restrict__ h1p, const float* __restrict__ dinv,
                        const float* __restrict__ b1, const float* __restrict__ W2, float* __restrict__ h2p, int N) {
    __shared__ float sW2[16], sb1[16];
    if (threadIdx.x < 16) { sW2[threadIdx.x] = W2[threadIdx.x]; sb1[threadIdx.x] = b1[threadIdx.x]; }
    __syncthreads();
    int i = blockIdx.x * blockDim.x + threadIdx.x;
    if (i >= N) return;
    float di = dinv[i], self = di * di, a = 0.f;
#pragma unroll
    for (int ff = 0; ff < 16; ++ff) {
        float v = agg1[i * 16 + ff] + h1p[i * 16 + ff] * self + sb1[ff];
        a = fmaf(fmaxf(v, 0.f), sW2[ff], a);
    }
    h2p[i] = a;
}
__global__ void fb_sc2(const int* __restrict__ row, const int* __restrict__ col, const float* __restrict__ dinv,
                       const float* __restrict__ h2p, float* __restrict__ out, int E) {
    int stride = gridDim.x * blockDim.x;
    for (int e = blockIdx.x * blockDim.x + threadIdx.x; e < E; e += stride) {
        int r = row[e], c = col[e];
        atomicAdd(&out[c], h2p[r] * dinv[r] * dinv[c]);
    }
}
__global__ void fb_fin2(float* __restrict__ out, const float* __restrict__ h2p, const float* __restrict__ dinv,
                        const float* __restrict__ b2, int N) {
    int i = blockIdx.x * blockDim.x + threadIdx.x;
    if (i < N) {
        float di = dinv[i];
        out[i] = fmaxf(out[i] + h2p[i] * di * di + b2[0], 0.f);
    }
}

// ============================ launcher ============================

extern "C" void kernel_launch(void* const* d_in, const int* in_sizes, int n_in,
                              void* d_out, int out_size, void* d_ws, size_t ws_size,
                              hipStream_t stream) {
    const float* x  = (const float*)d_in[0];
    const int*   ei = (const int*)d_in[1];
    const float* W1 = (const float*)d_in[2];
    const float* b1 = (const float*)d_in[3];
    const float* W2 = (const float*)d_in[4];
    const float* b2 = (const float*)d_in[5];
    float* out = (float*)d_out;
    const int* row = ei;
    const int* col = ei + NE;
    char* ws = (char*)d_ws;

    constexpr size_t OFF_EB = 0;                          // 25,600,000 B
    constexpr size_t OFF_X  = 25600000;                   // 6,600,000 B region (X = 6.4MB; g1 overlays dead part)
    constexpr size_t OFF_CT = OFF_X + 6600000;            // 4096 B
    constexpr size_t OFF_CB = OFF_CT + 4096;              // 4096 B
    constexpr size_t OFF_DI = OFF_CB + 4096;              // 400,000 B
    constexpr size_t OFF_H2 = OFF_DI + 400000;            // 400,000 B (unused, kept for layout stability)
    constexpr size_t OFF_GG = OFF_H2 + 400000;            // 400,000 B
    constexpr size_t WS_NEED = OFF_GG + 400000;           // ~33.4 MB

    if (ws_size >= WS_NEED) {
        int*   eb    = (int*)(ws + OFF_EB);
        int*   X     = (int*)(ws + OFF_X);
        int*   ctot  = (int*)(ws + OFF_CT);
        int*   cbase = (int*)(ws + OFF_CB);
        float* dinv  = (float*)(ws + OFF_DI);
        float* gg    = (float*)(ws + OFF_GG);
        // g1 [NN][16] (6.4 MB) overlays X's dead region (X[k], k<NBKT is all that
        // stays live after passB; bytes 32768+ of the X region are dead).
        float* g1    = (float*)(ws + OFF_X + 32768);

        histA<<<NB, 512, 0, stream>>>(col, X);
        scan1<<<NCH, 512, 0, stream>>>(X, ctot);
        scan2<<<1, 1024, 0, stream>>>(ctot, cbase);
        scan3<<<(TOTBINS + 255) / 256, 256, 0, stream>>>(X, cbase);
        passB<<<NB, 512, 0, stream>>>(row, col, X, eb);
        int gridK = (NBKT + 3) / 4;   // 1563
        passC<<<gridK, 256, 0, stream>>>(eb, X, x, W1, dinv, g1);
        passE<<<gridK, 256, 0, stream>>>(eb, X, g1, dinv, b1, W2, gg);
        passF<<<gridK, 256, 0, stream>>>(eb, X, gg, dinv, b2, out);
    } else {
        // fallback: global-atomic version (needs ~13.8 MB)
        float* dinv = (float*)(ws);
        float* h1p  = (float*)(ws + 524288);
        float* agg1 = (float*)(ws + 6924288);
        float* h2p  = (float*)(ws + 13324288);
        hipMemsetAsync(dinv, 0, NN * sizeof(float), stream);
        hipMemsetAsync(agg1, 0, NN * 16 * sizeof(float), stream);
        hipMemsetAsync(out, 0, NN * sizeof(float), stream);
        const int B = 256;
        int gridN = (NN + B - 1) / B;
        fb_deg<<<4096, B, 0, stream>>>(col, dinv, NE);
        fb_dinv<<<gridN, B, 0, stream>>>(dinv, NN);
        fb_h1p<<<gridN, B, 0, stream>>>(x, W1, h1p, NN);
        fb_sc1<<<8192, B, 0, stream>>>(row, col, dinv, h1p, agg1, (long)NE * 16);
        fb_fin1<<<gridN, B, 0, stream>>>(agg1, h1p, dinv, b1, W2, h2p, NN);
        fb_sc2<<<4096, B, 0, stream>>>(row, col, dinv, h2p, out, NE);
        fb_fin2<<<gridN, B, 0, stream>>>(out, h2p, dinv, b2, NN);
    }
}

// Round 9
// 273.402 us; speedup vs baseline: 1.9000x; 1.0805x over previous
//
#include <hip/hip_runtime.h>
#include <hip/hip_fp16.h>

#define NN 100000
#define NE 6400000
#define BSZ 16                    // nodes per bucket (NN = NBKT*BSZ exactly)
#define NBKT 6250
#define NB 256                    // sort chunks
#define CHUNK 25000               // NE/NB exactly
#define TOTBINS (NBKT * NB)       // 1,600,000
#define SC1 2048                  // elems per scan1 block
#define NCH ((TOTBINS + SC1 - 1) / SC1)   // 782
#define CAP 2176                  // max staged edges per bucket (mean 1024, sigma 32)

// ============================ fast path ============================

// X[b*NBKT + k] = count of edges in chunk b destined to bucket k
__global__ __launch_bounds__(512) void histA(const int* __restrict__ col, int* __restrict__ X) {
    __shared__ int h[NBKT];
    for (int i = threadIdx.x; i < NBKT; i += 512) h[i] = 0;
    __syncthreads();
    const int* c = col + blockIdx.x * CHUNK;
    for (int i = threadIdx.x; i < CHUNK; i += 512)
        atomicAdd(&h[c[i] >> 4], 1);
    __syncthreads();
    int* o = X + blockIdx.x * NBKT;
    for (int i = threadIdx.x; i < NBKT; i += 512) o[i] = h[i];
}

// in-place exclusive scan over logical order idx = k*NB + b (storage X[b*NBKT+k])
__global__ __launch_bounds__(512) void scan1(int* __restrict__ X, int* __restrict__ ctot) {
    __shared__ int buf[SC1];
    __shared__ int ts[512];
    int base = blockIdx.x * SC1;
    for (int j = threadIdx.x; j < SC1; j += 512) {
        int idx = base + j; int v = 0;
        if (idx < TOTBINS) { int k = idx >> 8, b = idx & 255; v = X[b * NBKT + k]; }
        buf[j] = v;
    }
    __syncthreads();
    int j0 = threadIdx.x * 4;
    int a0 = buf[j0], a1 = buf[j0 + 1], a2 = buf[j0 + 2], a3 = buf[j0 + 3];
    int s = a0 + a1 + a2 + a3;
    ts[threadIdx.x] = s;
    __syncthreads();
    for (int off = 1; off < 512; off <<= 1) {
        int u = (threadIdx.x >= off) ? ts[threadIdx.x - off] : 0;
        __syncthreads();
        ts[threadIdx.x] += u;
        __syncthreads();
    }
    int e0 = ts[threadIdx.x] - s;
    int ev[4] = {e0, e0 + a0, e0 + a0 + a1, e0 + a0 + a1 + a2};
#pragma unroll
    for (int t = 0; t < 4; ++t) {
        int idx = base + j0 + t;
        if (idx < TOTBINS) { int k = idx >> 8, b = idx & 255; X[b * NBKT + k] = ev[t]; }
    }
    if (threadIdx.x == 511) ctot[blockIdx.x] = ts[511];
}

__global__ void scan2(const int* __restrict__ ctot, int* __restrict__ cbase) {
    __shared__ int ts[1024];
    int t = threadIdx.x;
    int orig = (t < NCH) ? ctot[t] : 0;
    ts[t] = orig;
    __syncthreads();
    for (int off = 1; off < 1024; off <<= 1) {
        int u = (t >= off) ? ts[t - off] : 0;
        __syncthreads();
        ts[t] += u;
        __syncthreads();
    }
    if (t < NCH) cbase[t] = ts[t] - orig;
}

__global__ __launch_bounds__(256) void scan3(int* __restrict__ X, const int* __restrict__ cbase) {
    int m = blockIdx.x * 256 + threadIdx.x;
    if (m >= TOTBINS) return;
    int b = m / NBKT;
    int k = m - b * NBKT;
    int idx = (k << 8) | b;
    X[m] += cbase[idx >> 11];     // SC1 = 2048
}

// scatter edges into bucket-sorted eb; pack (slot<<17 | row). XCD-clustered chunks.
__global__ __launch_bounds__(512) void passB(const int* __restrict__ row, const int* __restrict__ col,
                                             const int* __restrict__ X, int* __restrict__ eb) {
    __shared__ int cur[NBKT];
    int b = ((blockIdx.x & 7) << 5) | (blockIdx.x >> 3);   // XCD-clustered chunk id
    const int* st = X + b * NBKT;
    for (int i = threadIdx.x; i < NBKT; i += 512) cur[i] = st[i];
    __syncthreads();
    const int* c = col + b * CHUNK;
    const int* r = row + b * CHUNK;
    for (int i = threadIdx.x; i < CHUNK; i += 512) {
        int cc = c[i];
        int pos = atomicAdd(&cur[cc >> 4], 1);
        eb[pos] = r[i] | ((cc & 15) << 17);
    }
}

// passS: per-bucket counting sort by node slot (ballot ranking, in-place via LDS stage),
// + degree -> dinv, run starts rs, fused g1h = fp16(dinv * (x @ W1)).
__global__ __launch_bounds__(256) void passS(int* __restrict__ eb, const int* __restrict__ X,
                                             const float* __restrict__ x, const float* __restrict__ W1,
                                             float* __restrict__ dinv, int* __restrict__ rs,
                                             unsigned short* __restrict__ g1h) {
    __shared__ float sW[144];
    __shared__ int stage[4][CAP];
    for (int i = threadIdx.x; i < 144; i += 256) sW[i] = W1[i];
    __syncthreads();
    if (blockIdx.x == 0 && threadIdx.x == 0) rs[NN] = NE;   // sentinel
    int w = threadIdx.x >> 6, lane = threadIdx.x & 63;
    int k = blockIdx.x * 4 + w;
    if (k >= NBKT) return;
    int s = X[k];
    int e = (k + 1 < NBKT) ? X[k + 1] : NE;
    int n = e - s;
    if (n > CAP) n = CAP;          // 36-sigma guard, statistically unreachable
    int* st = stage[w];
    for (int i = lane; i < n; i += 64) st[i] = eb[s + i];
    // per-slot counts: lane t (t<16) accumulates count of slot==t
    int cnt = 0;
    for (int i0 = 0; i0 < n; i0 += 64) {
        int i = i0 + lane;
        int slot = (i < n) ? ((st[i] >> 17) & 15) : 16;
#pragma unroll
        for (int t = 0; t < 16; ++t) {
            unsigned long long m = __ballot(slot == t);
            if (lane == t) cnt += __popcll(m);
        }
    }
    // exclusive prefix over lanes 0..15
    int pf = cnt;
#pragma unroll
    for (int d = 1; d < 16; d <<= 1) {
        int u = __shfl(pf, lane - d);
        if (lane >= d) pf += u;
    }
    int excl = pf - cnt;
    float dval = rsqrtf((float)cnt + 1.f);
    if (lane < 16) {
        int node = k * BSZ + lane;
        dinv[node] = dval;
        rs[node] = s + excl;
    }
    // rank & scatter (in place into eb[s..e))
    int rb = excl;                 // run cursor, valid in lanes 0..15
    for (int i0 = 0; i0 < n; i0 += 64) {
        int i = i0 + lane;
        int p = (i < n) ? st[i] : 0;
        int slot = (i < n) ? ((p >> 17) & 15) : 16;
        unsigned long long mymask = 0; int addc = 0;
#pragma unroll
        for (int t = 0; t < 16; ++t) {
            unsigned long long m = __ballot(slot == t);
            if (slot == t) mymask = m;
            if (lane == t) addc = __popcll(m);
        }
        int base = __shfl(rb, slot & 15);
        int rank = __popcll(mymask & ((1ull << lane) - 1ull));
        if (i < n) eb[s + base + rank] = p;
        if (lane < 16) rb += addc;
    }
    // fused g1h: lanes (nd = lane>>2, fq = lane&3), 4 features each
    int nd = lane >> 2, fq = lane & 3;
    int node = k * BSZ + nd;
    float di = __shfl(dval, nd);
    float xr[9];
#pragma unroll
    for (int q = 0; q < 9; ++q) xr[q] = x[node * 9 + q];
    float a[4];
#pragma unroll
    for (int j = 0; j < 4; ++j) {
        int f = fq * 4 + j;
        float acc = 0.f;
#pragma unroll
        for (int q = 0; q < 9; ++q) acc = fmaf(xr[q], sW[q * 16 + f], acc);
        a[j] = acc * di;
    }
    __half2 h0 = __floats2half2_rn(a[0], a[1]);
    __half2 h1 = __floats2half2_rn(a[2], a[3]);
    uint2 stv;
    stv.x = *(unsigned int*)&h0;
    stv.y = *(unsigned int*)&h1;
    *(uint2*)((char*)g1h + (size_t)node * 32 + fq * 8) = stv;
}

// layer-1 aggregate over node-sorted runs (maskless) + relu + layer-2 dot.
// wave per bucket; 16 edge-groups x 4 feature-lanes; fp16 gathers (L2-resident 3.2 MB).
__global__ __launch_bounds__(256) void passE(const int* __restrict__ eb, const int* __restrict__ rs,
                                             const unsigned short* __restrict__ g1h,
                                             const float* __restrict__ dinv,
                                             const float* __restrict__ b1, const float* __restrict__ W2,
                                             float* __restrict__ gg) {
    __shared__ float sb1[16], sW2[16];
    if (threadIdx.x < 16) { sb1[threadIdx.x] = b1[threadIdx.x]; sW2[threadIdx.x] = W2[threadIdx.x]; }
    __syncthreads();
    int w = threadIdx.x >> 6, lane = threadIdx.x & 63;
    int k = blockIdx.x * 4 + w;
    if (k >= NBKT) return;
    int g = lane >> 2, fq = lane & 3;
    const char* gb = (const char*)g1h;
    for (int nd = 0; nd < 16; ++nd) {
        int node = k * BSZ + nd;
        int rsv = rs[node], rev = rs[node + 1];
        float4 acc = make_float4(0.f, 0.f, 0.f, 0.f);
        for (int i = rsv + g; i < rev; i += 16) {
            int r = eb[i] & 0x1FFFF;
            uint2 hv = *(const uint2*)(gb + (size_t)r * 32 + fq * 8);
            __half2 h0 = *(__half2*)&hv.x, h1 = *(__half2*)&hv.y;
            float2 f0 = __half22float2(h0), f1 = __half22float2(h1);
            acc.x += f0.x; acc.y += f0.y; acc.z += f1.x; acc.w += f1.y;
        }
#pragma unroll
        for (int d = 4; d < 64; d <<= 1) {
            acc.x += __shfl_xor(acc.x, d);
            acc.y += __shfl_xor(acc.y, d);
            acc.z += __shfl_xor(acc.z, d);
            acc.w += __shfl_xor(acc.w, d);
        }
        float di = dinv[node];
        uint2 sv = *(const uint2*)(gb + (size_t)node * 32 + fq * 8);
        __half2 s0 = *(__half2*)&sv.x, s1 = *(__half2*)&sv.y;
        float2 gs0 = __half22float2(s0), gs1 = __half22float2(s1);
        int f0 = fq * 4;
        float v0 = fmaxf(di * (acc.x + gs0.x) + sb1[f0 + 0], 0.f);
        float v1 = fmaxf(di * (acc.y + gs0.y) + sb1[f0 + 1], 0.f);
        float v2 = fmaxf(di * (acc.z + gs1.x) + sb1[f0 + 2], 0.f);
        float v3 = fmaxf(di * (acc.w + gs1.y) + sb1[f0 + 3], 0.f);
        float part = v0 * sW2[f0] + v1 * sW2[f0 + 1] + v2 * sW2[f0 + 2] + v3 * sW2[f0 + 3];
        part += __shfl_xor(part, 1);
        part += __shfl_xor(part, 2);
        if (lane == 0) gg[node] = di * part;
    }
}

// layer-2 aggregate over node-sorted runs + finalize. wave per bucket.
__global__ __launch_bounds__(256) void passF(const int* __restrict__ eb, const int* __restrict__ rs,
                                             const float* __restrict__ gg, const float* __restrict__ dinv,
                                             const float* __restrict__ b2, float* __restrict__ out) {
    int w = threadIdx.x >> 6, lane = threadIdx.x & 63;
    int k = blockIdx.x * 4 + w;
    if (k >= NBKT) return;
    float b = b2[0];
    for (int nd = 0; nd < 16; ++nd) {
        int node = k * BSZ + nd;
        int rsv = rs[node], rev = rs[node + 1];
        float a = 0.f;
        for (int i = rsv + lane; i < rev; i += 64) a += gg[eb[i] & 0x1FFFF];
#pragma unroll
        for (int d = 1; d < 64; d <<= 1) a += __shfl_xor(a, d);
        if (lane == 0) out[node] = fmaxf(dinv[node] * (a + gg[node]) + b, 0.f);
    }
}

// ============================ fallback path (global atomics) ============================

__global__ void fb_deg(const int* __restrict__ col, float* __restrict__ deg, int E) {
    int stride = gridDim.x * blockDim.x;
    for (int i = blockIdx.x * blockDim.x + threadIdx.x; i < E; i += stride)
        atomicAdd(&deg[col[i]], 1.0f);
}
__global__ void fb_dinv(float* __restrict__ d, int N) {
    int i = blockIdx.x * blockDim.x + threadIdx.x;
    if (i < N) d[i] = rsqrtf(d[i] + 1.0f);
}
__global__ void fb_h1p(const float* __restrict__ x, const float* __restrict__ W1, float* __restrict__ h1p, int N) {
    __shared__ float sW[144];
    if (threadIdx.x < 144) sW[threadIdx.x] = W1[threadIdx.x];
    __syncthreads();
    int i = blockIdx.x * blockDim.x + threadIdx.x;
    if (i >= N) return;
    float xi[9];
#pragma unroll
    for (int q = 0; q < 9; ++q) xi[q] = x[i * 9 + q];
#pragma unroll
    for (int ff = 0; ff < 16; ++ff) {
        float a = 0.f;
#pragma unroll
        for (int q = 0; q < 9; ++q) a = fmaf(xi[q], sW[q * 16 + ff], a);
        h1p[i * 16 + ff] = a;
    }
}
__global__ void fb_sc1(const int* __restrict__ row, const int* __restrict__ col, const float* __restrict__ dinv,
                       const float* __restrict__ h1p, float* __restrict__ agg1, long total) {
    long stride = (long)gridDim.x * blockDim.x;
    for (long t = (long)blockIdx.x * blockDim.x + threadIdx.x; t < total; t += stride) {
        int e = (int)(t >> 4), ff = (int)(t & 15);
        int r = row[e], c = col[e];
        atomicAdd(&agg1[c * 16 + ff], h1p[r * 16 + ff] * dinv[r] * dinv[c]);
    }
}
__global__ void fb_fin1(const float* __restrict__ agg1, const float* __restrict__ h1p, const float* __restrict__ dinv,
                        const float* __restrict__ b1, const float* __restrict__ W2, float* __restrict__ h2p, int N) {
    __shared__ float sW2[16], sb1[16];
    if (threadIdx.x < 16) { sW2[threadIdx.x] = W2[threadIdx.x]; sb1[threadIdx.x] = b1[threadIdx.x]; }
    __syncthreads();
    int i = blockIdx.x * blockDim.x + threadIdx.x;
    if (i >= N) return;
    float di = dinv[i], self = di * di, a = 0.f;
#pragma unroll
    for (int ff = 0; ff < 16; ++ff) {
        float v = agg1[i * 16 + ff] + h1p[i * 16 + ff] * self + sb1[ff];
        a = fmaf(fmaxf(v, 0.f), sW2[ff], a);
    }
    h2p[i] = a;
}
__global__ void fb_sc2(const int* __restrict__ row, const int* __restrict__ col, const float* __restrict__ dinv,
                       const float* __restrict__ h2p, float* __restrict__ out, int E) {
    int stride = gridDim.x * blockDim.x;
    for (int e = blockIdx.x * blockDim.x + threadIdx.x; e < E; e += stride) {
        int r = row[e], c = col[e];
        atomicAdd(&out[c], h2p[r] * dinv[r] * dinv[c]);
    }
}
__global__ void fb_fin2(float* __restrict__ out, const float* __restrict__ h2p, const float* __restrict__ dinv,
                        const float* __restrict__ b2, int N) {
    int i = blockIdx.x * blockDim.x + threadIdx.x;
    if (i < N) {
        float di = dinv[i];
        out[i] = fmaxf(out[i] + h2p[i] * di * di + b2[0], 0.f);
    }
}

// ============================ launcher ============================

extern "C" void kernel_launch(void* const* d_in, const int* in_sizes, int n_in,
                              void* d_out, int out_size, void* d_ws, size_t ws_size,
                              hipStream_t stream) {
    const float* x  = (const float*)d_in[0];
    const int*   ei = (const int*)d_in[1];
    const float* W1 = (const float*)d_in[2];
    const float* b1 = (const float*)d_in[3];
    const float* W2 = (const float*)d_in[4];
    const float* b2 = (const float*)d_in[5];
    float* out = (float*)d_out;
    const int* row = ei;
    const int* col = ei + NE;
    char* ws = (char*)d_ws;

    constexpr size_t OFF_EB = 0;                          // 25,600,000 B
    constexpr size_t OFF_X  = 25600000;                   // 6,600,000 B region (X live = first 25 KB after passB; g1h overlays at +32 KB)
    constexpr size_t OFF_CT = OFF_X + 6600000;            // 4096 B
    constexpr size_t OFF_CB = OFF_CT + 4096;              // 4096 B
    constexpr size_t OFF_DI = OFF_CB + 4096;              // 400,000 B
    constexpr size_t OFF_RS = OFF_DI + 400000;            // 400,128 B (rs[NN+1])
    constexpr size_t OFF_GG = OFF_RS + 400128;            // 400,000 B
    constexpr size_t WS_NEED = OFF_GG + 400000;           // ~33.4 MB (same as r8, proven)

    if (ws_size >= WS_NEED) {
        int*   eb    = (int*)(ws + OFF_EB);
        int*   X     = (int*)(ws + OFF_X);
        int*   ctot  = (int*)(ws + OFF_CT);
        int*   cbase = (int*)(ws + OFF_CB);
        float* dinv  = (float*)(ws + OFF_DI);
        int*   rs    = (int*)(ws + OFF_RS);
        float* gg    = (float*)(ws + OFF_GG);
        unsigned short* g1h = (unsigned short*)(ws + OFF_X + 32768);  // 3.2 MB fp16 [NN][16]

        histA<<<NB, 512, 0, stream>>>(col, X);
        scan1<<<NCH, 512, 0, stream>>>(X, ctot);
        scan2<<<1, 1024, 0, stream>>>(ctot, cbase);
        scan3<<<(TOTBINS + 255) / 256, 256, 0, stream>>>(X, cbase);
        passB<<<NB, 512, 0, stream>>>(row, col, X, eb);
        int gridK = (NBKT + 3) / 4;   // 1563
        passS<<<gridK, 256, 0, stream>>>(eb, X, x, W1, dinv, rs, g1h);
        passE<<<gridK, 256, 0, stream>>>(eb, rs, g1h, dinv, b1, W2, gg);
        passF<<<gridK, 256, 0, stream>>>(eb, rs, gg, dinv, b2, out);
    } else {
        // fallback: global-atomic version (needs ~13.8 MB)
        float* dinv = (float*)(ws);
        float* h1p  = (float*)(ws + 524288);
        float* agg1 = (float*)(ws + 6924288);
        float* h2p  = (float*)(ws + 13324288);
        hipMemsetAsync(dinv, 0, NN * sizeof(float), stream);
        hipMemsetAsync(agg1, 0, NN * 16 * sizeof(float), stream);
        hipMemsetAsync(out, 0, NN * sizeof(float), stream);
        const int B = 256;
        int gridN = (NN + B - 1) / B;
        fb_deg<<<4096, B, 0, stream>>>(col, dinv, NE);
        fb_dinv<<<gridN, B, 0, stream>>>(dinv, NN);
        fb_h1p<<<gridN, B, 0, stream>>>(x, W1, h1p, NN);
        fb_sc1<<<8192, B, 0, stream>>>(row, col, dinv, h1p, agg1, (long)NE * 16);
        fb_fin1<<<gridN, B, 0, stream>>>(agg1, h1p, dinv, b1, W2, h2p, NN);
        fb_sc2<<<4096, B, 0, stream>>>(row, col, dinv, h2p, out, NE);
        fb_fin2<<<gridN, B, 0, stream>>>(out, h2p, dinv, b2, NN);
    }
}

// Round 10
// 258.300 us; speedup vs baseline: 2.0111x; 1.0585x over previous
//
#include <hip/hip_runtime.h>
#include <hip/hip_fp16.h>

#define NN 100000
#define NE 6400000
#define BSZ 16                    // nodes per fine bucket
#define NBKT 6250                 // fine buckets = NN/16
#define NCO 782                   // coarse buckets (128 nodes) = ceil(NN/128)
#define NB 256                    // sort chunks
#define CHUNK 25000               // NE/NB exactly
#define TOTB (NCO * NB)           // 200,192
#define SC1 2048
#define NCH ((TOTB + SC1 - 1) / SC1)   // 98
#define CAPS 9216                 // B2 segment cap (mean 8192, sigma ~90)
#define CAP 2176                  // passS per-fine-bucket stage cap

// ============================ fast path ============================

// X[b*NCO + c] = count of edges in chunk b destined to coarse bucket c
__global__ __launch_bounds__(512) void histA(const int* __restrict__ col, int* __restrict__ X) {
    __shared__ int h[NCO];
    for (int i = threadIdx.x; i < NCO; i += 512) h[i] = 0;
    __syncthreads();
    const int* c = col + blockIdx.x * CHUNK;
    for (int i = threadIdx.x; i < CHUNK; i += 512)
        atomicAdd(&h[c[i] >> 7], 1);
    __syncthreads();
    int* o = X + blockIdx.x * NCO;
    for (int i = threadIdx.x; i < NCO; i += 512) o[i] = h[i];
}

// in-place exclusive scan over logical order idx = c*NB + b (storage X[b*NCO+c])
__global__ __launch_bounds__(512) void scan1(int* __restrict__ X, int* __restrict__ ctot) {
    __shared__ int buf[SC1];
    __shared__ int ts[512];
    int base = blockIdx.x * SC1;
    for (int j = threadIdx.x; j < SC1; j += 512) {
        int idx = base + j; int v = 0;
        if (idx < TOTB) { int k = idx >> 8, b = idx & 255; v = X[b * NCO + k]; }
        buf[j] = v;
    }
    __syncthreads();
    int j0 = threadIdx.x * 4;
    int a0 = buf[j0], a1 = buf[j0 + 1], a2 = buf[j0 + 2], a3 = buf[j0 + 3];
    int s = a0 + a1 + a2 + a3;
    ts[threadIdx.x] = s;
    __syncthreads();
    for (int off = 1; off < 512; off <<= 1) {
        int u = (threadIdx.x >= off) ? ts[threadIdx.x - off] : 0;
        __syncthreads();
        ts[threadIdx.x] += u;
        __syncthreads();
    }
    int e0 = ts[threadIdx.x] - s;
    int ev[4] = {e0, e0 + a0, e0 + a0 + a1, e0 + a0 + a1 + a2};
#pragma unroll
    for (int t = 0; t < 4; ++t) {
        int idx = base + j0 + t;
        if (idx < TOTB) { int k = idx >> 8, b = idx & 255; X[b * NCO + k] = ev[t]; }
    }
    if (threadIdx.x == 511) ctot[blockIdx.x] = ts[511];
}

__global__ void scan2(const int* __restrict__ ctot, int* __restrict__ cbase) {
    __shared__ int ts[1024];
    int t = threadIdx.x;
    int orig = (t < NCH) ? ctot[t] : 0;
    ts[t] = orig;
    __syncthreads();
    for (int off = 1; off < 1024; off <<= 1) {
        int u = (t >= off) ? ts[t - off] : 0;
        __syncthreads();
        ts[t] += u;
        __syncthreads();
    }
    if (t < NCH) cbase[t] = ts[t] - orig;
}

__global__ __launch_bounds__(256) void scan3(int* __restrict__ X, const int* __restrict__ cbase) {
    int m = blockIdx.x * 256 + threadIdx.x;
    if (m >= TOTB) return;
    int b = m / NCO;
    int k = m - b * NCO;
    int idx = (k << 8) | b;
    X[m] += cbase[idx >> 11];     // SC1 = 2048
}

// level-1 scatter into coarse-sorted eb; pack row | fineLocal<<17 | slot<<20
__global__ __launch_bounds__(512) void passB1(const int* __restrict__ row, const int* __restrict__ col,
                                              const int* __restrict__ X, int* __restrict__ eb) {
    __shared__ int cur[NCO];
    int b = ((blockIdx.x & 7) << 5) | (blockIdx.x >> 3);   // XCD-clustered chunk id
    const int* st = X + b * NCO;
    for (int i = threadIdx.x; i < NCO; i += 512) cur[i] = st[i];
    __syncthreads();
    const int* c = col + b * CHUNK;
    const int* r = row + b * CHUNK;
    for (int i = threadIdx.x; i < CHUNK; i += 512) {
        int cc = c[i];
        int pos = atomicAdd(&cur[cc >> 7], 1);
        eb[pos] = r[i] | (((cc >> 4) & 7) << 17) | ((cc & 15) << 20);
    }
}

// level-2: per coarse bucket, ballot-rank sort into 8 fine(16-node) buckets, in place.
// Atomic-free. Writes fine starts to XF. Output word: (slot<<17 | row) for passS.
__global__ __launch_bounds__(256) void passB2(int* __restrict__ eb, const int* __restrict__ X,
                                              int* __restrict__ XF) {
    __shared__ int seg[CAPS];
    __shared__ int cnt4[4][8];
    __shared__ int wbase[4][8];
    int c = blockIdx.x;
    int s = X[c];
    int e = (c + 1 < NCO) ? X[c + 1] : NE;
    int n = e - s;
    if (n > CAPS) n = CAPS;       // 11-sigma guard, unreachable
    for (int i = threadIdx.x; i < n; i += 256) seg[i] = eb[s + i];
    __syncthreads();
    int w = threadIdx.x >> 6, lane = threadIdx.x & 63;
    int q0 = (n + 3) >> 2;
    int ws = w * q0;
    int we = ws + q0; if (we > n) we = n;
    // count 8 fine slots in my wave's slice
    int cnt = 0;
    for (int i0 = ws; i0 < we; i0 += 64) {
        int i = i0 + lane;
        int f = (i < we) ? ((seg[i] >> 17) & 7) : 8;
#pragma unroll
        for (int t = 0; t < 8; ++t) {
            unsigned long long m = __ballot(f == t);
            if (lane == t) cnt += __popcll(m);
        }
    }
    if (lane < 8) cnt4[w][lane] = cnt;
    __syncthreads();
    if (threadIdx.x == 0) {
        int acc = 0;
#pragma unroll
        for (int f = 0; f < 8; ++f) {
            XF[c * 8 + f] = s + acc;
            for (int q = 0; q < 4; ++q) { wbase[q][f] = acc; acc += cnt4[q][f]; }
        }
    }
    __syncthreads();
    // scatter: wave-local running cursors per fine slot (lane f<8 holds cursor)
    int rb = (lane < 8) ? wbase[w][lane] : 0;
    for (int i0 = ws; i0 < we; i0 += 64) {
        int i = i0 + lane;
        int p = (i < we) ? seg[i] : 0;
        int f = (i < we) ? ((p >> 17) & 7) : 8;
        unsigned long long mymask = 0; int addc = 0;
#pragma unroll
        for (int t = 0; t < 8; ++t) {
            unsigned long long m = __ballot(f == t);
            if (f == t) mymask = m;
            if (lane == t) addc = __popcll(m);
        }
        int base = __shfl(rb, f & 7);
        int rank = __popcll(mymask & ((1ull << lane) - 1ull));
        if (i < we) eb[s + base + rank] = (p & 0x1FFFF) | (((p >> 20) & 15) << 17);
        if (lane < 8) rb += addc;
    }
}

// passS: per-fine-bucket counting sort by node slot (ballot ranking, LDS stage),
// + degree -> dinv, run starts rs, fused g1h = fp16(dinv * (x @ W1)).
__global__ __launch_bounds__(256) void passS(int* __restrict__ eb, const int* __restrict__ XF,
                                             const float* __restrict__ x, const float* __restrict__ W1,
                                             float* __restrict__ dinv, int* __restrict__ rs,
                                             unsigned short* __restrict__ g1h) {
    __shared__ float sW[144];
    __shared__ int stage[4][CAP];
    for (int i = threadIdx.x; i < 144; i += 256) sW[i] = W1[i];
    __syncthreads();
    if (blockIdx.x == 0 && threadIdx.x == 0) rs[NN] = NE;   // sentinel
    int w = threadIdx.x >> 6, lane = threadIdx.x & 63;
    int k = blockIdx.x * 4 + w;
    if (k >= NBKT) return;
    int s = XF[k];
    int e = (k + 1 < NBKT) ? XF[k + 1] : NE;
    int n = e - s;
    if (n > CAP) n = CAP;          // 36-sigma guard
    int* st = stage[w];
    for (int i = lane; i < n; i += 64) st[i] = eb[s + i];
    int cnt = 0;
    for (int i0 = 0; i0 < n; i0 += 64) {
        int i = i0 + lane;
        int slot = (i < n) ? ((st[i] >> 17) & 15) : 16;
#pragma unroll
        for (int t = 0; t < 16; ++t) {
            unsigned long long m = __ballot(slot == t);
            if (lane == t) cnt += __popcll(m);
        }
    }
    int pf = cnt;
#pragma unroll
    for (int d = 1; d < 16; d <<= 1) {
        int u = __shfl(pf, lane - d);
        if (lane >= d) pf += u;
    }
    int excl = pf - cnt;
    float dval = rsqrtf((float)cnt + 1.f);
    if (lane < 16) {
        int node = k * BSZ + lane;
        dinv[node] = dval;
        rs[node] = s + excl;
    }
    int rb = excl;
    for (int i0 = 0; i0 < n; i0 += 64) {
        int i = i0 + lane;
        int p = (i < n) ? st[i] : 0;
        int slot = (i < n) ? ((p >> 17) & 15) : 16;
        unsigned long long mymask = 0; int addc = 0;
#pragma unroll
        for (int t = 0; t < 16; ++t) {
            unsigned long long m = __ballot(slot == t);
            if (slot == t) mymask = m;
            if (lane == t) addc = __popcll(m);
        }
        int base = __shfl(rb, slot & 15);
        int rank = __popcll(mymask & ((1ull << lane) - 1ull));
        if (i < n) eb[s + base + rank] = p;
        if (lane < 16) rb += addc;
    }
    // fused g1h
    int nd = lane >> 2, fq = lane & 3;
    int node = k * BSZ + nd;
    float di = __shfl(dval, nd);
    float xr[9];
#pragma unroll
    for (int q = 0; q < 9; ++q) xr[q] = x[node * 9 + q];
    float a[4];
#pragma unroll
    for (int j = 0; j < 4; ++j) {
        int f = fq * 4 + j;
        float acc = 0.f;
#pragma unroll
        for (int q = 0; q < 9; ++q) acc = fmaf(xr[q], sW[q * 16 + f], acc);
        a[j] = acc * di;
    }
    __half2 h0 = __floats2half2_rn(a[0], a[1]);
    __half2 h1 = __floats2half2_rn(a[2], a[3]);
    uint2 stv;
    stv.x = *(unsigned int*)&h0;
    stv.y = *(unsigned int*)&h1;
    *(uint2*)((char*)g1h + (size_t)node * 32 + fq * 8) = stv;
}

// layer-1 aggregate over node-sorted runs + relu + layer-2 dot.
__global__ __launch_bounds__(256) void passE(const int* __restrict__ eb, const int* __restrict__ rs,
                                             const unsigned short* __restrict__ g1h,
                                             const float* __restrict__ dinv,
                                             const float* __restrict__ b1, const float* __restrict__ W2,
                                             float* __restrict__ gg) {
    __shared__ float sb1[16], sW2[16];
    if (threadIdx.x < 16) { sb1[threadIdx.x] = b1[threadIdx.x]; sW2[threadIdx.x] = W2[threadIdx.x]; }
    __syncthreads();
    int w = threadIdx.x >> 6, lane = threadIdx.x & 63;
    int k = blockIdx.x * 4 + w;
    if (k >= NBKT) return;
    int g = lane >> 2, fq = lane & 3;
    const char* gb = (const char*)g1h;
    for (int nd = 0; nd < 16; ++nd) {
        int node = k * BSZ + nd;
        int rsv = rs[node], rev = rs[node + 1];
        float4 acc = make_float4(0.f, 0.f, 0.f, 0.f);
        for (int i = rsv + g; i < rev; i += 16) {
            int r = eb[i] & 0x1FFFF;
            uint2 hv = *(const uint2*)(gb + (size_t)r * 32 + fq * 8);
            __half2 h0 = *(__half2*)&hv.x, h1 = *(__half2*)&hv.y;
            float2 f0 = __half22float2(h0), f1 = __half22float2(h1);
            acc.x += f0.x; acc.y += f0.y; acc.z += f1.x; acc.w += f1.y;
        }
#pragma unroll
        for (int d = 4; d < 64; d <<= 1) {
            acc.x += __shfl_xor(acc.x, d);
            acc.y += __shfl_xor(acc.y, d);
            acc.z += __shfl_xor(acc.z, d);
            acc.w += __shfl_xor(acc.w, d);
        }
        float di = dinv[node];
        uint2 sv = *(const uint2*)(gb + (size_t)node * 32 + fq * 8);
        __half2 s0 = *(__half2*)&sv.x, s1 = *(__half2*)&sv.y;
        float2 gs0 = __half22float2(s0), gs1 = __half22float2(s1);
        int f0 = fq * 4;
        float v0 = fmaxf(di * (acc.x + gs0.x) + sb1[f0 + 0], 0.f);
        float v1 = fmaxf(di * (acc.y + gs0.y) + sb1[f0 + 1], 0.f);
        float v2 = fmaxf(di * (acc.z + gs1.x) + sb1[f0 + 2], 0.f);
        float v3 = fmaxf(di * (acc.w + gs1.y) + sb1[f0 + 3], 0.f);
        float part = v0 * sW2[f0] + v1 * sW2[f0 + 1] + v2 * sW2[f0 + 2] + v3 * sW2[f0 + 3];
        part += __shfl_xor(part, 1);
        part += __shfl_xor(part, 2);
        if (lane == 0) gg[node] = di * part;
    }
}

// layer-2 aggregate over node-sorted runs + finalize.
__global__ __launch_bounds__(256) void passF(const int* __restrict__ eb, const int* __restrict__ rs,
                                             const float* __restrict__ gg, const float* __restrict__ dinv,
                                             const float* __restrict__ b2, float* __restrict__ out) {
    int w = threadIdx.x >> 6, lane = threadIdx.x & 63;
    int k = blockIdx.x * 4 + w;
    if (k >= NBKT) return;
    float b = b2[0];
    for (int nd = 0; nd < 16; ++nd) {
        int node = k * BSZ + nd;
        int rsv = rs[node], rev = rs[node + 1];
        float a = 0.f;
        for (int i = rsv + lane; i < rev; i += 64) a += gg[eb[i] & 0x1FFFF];
#pragma unroll
        for (int d = 1; d < 64; d <<= 1) a += __shfl_xor(a, d);
        if (lane == 0) out[node] = fmaxf(dinv[node] * (a + gg[node]) + b, 0.f);
    }
}

// ============================ fallback path (global atomics) ============================

__global__ void fb_deg(const int* __restrict__ col, float* __restrict__ deg, int E) {
    int stride = gridDim.x * blockDim.x;
    for (int i = blockIdx.x * blockDim.x + threadIdx.x; i < E; i += stride)
        atomicAdd(&deg[col[i]], 1.0f);
}
__global__ void fb_dinv(float* __restrict__ d, int N) {
    int i = blockIdx.x * blockDim.x + threadIdx.x;
    if (i < N) d[i] = rsqrtf(d[i] + 1.0f);
}
__global__ void fb_h1p(const float* __restrict__ x, const float* __restrict__ W1, float* __restrict__ h1p, int N) {
    __shared__ float sW[144];
    if (threadIdx.x < 144) sW[threadIdx.x] = W1[threadIdx.x];
    __syncthreads();
    int i = blockIdx.x * blockDim.x + threadIdx.x;
    if (i >= N) return;
    float xi[9];
#pragma unroll
    for (int q = 0; q < 9; ++q) xi[q] = x[i * 9 + q];
#pragma unroll
    for (int ff = 0; ff < 16; ++ff) {
        float a = 0.f;
#pragma unroll
        for (int q = 0; q < 9; ++q) a = fmaf(xi[q], sW[q * 16 + ff], a);
        h1p[i * 16 + ff] = a;
    }
}
__global__ void fb_sc1(const int* __restrict__ row, const int* __restrict__ col, const float* __restrict__ dinv,
                       const float* __restrict__ h1p, float* __restrict__ agg1, long total) {
    long stride = (long)gridDim.x * blockDim.x;
    for (long t = (long)blockIdx.x * blockDim.x + threadIdx.x; t < total; t += stride) {
        int e = (int)(t >> 4), ff = (int)(t & 15);
        int r = row[e], c = col[e];
        atomicAdd(&agg1[c * 16 + ff], h1p[r * 16 + ff] * dinv[r] * dinv[c]);
    }
}
__global__ void fb_fin1(const float* __restrict__ agg1, const float* __restrict__ h1p, const float* __restrict__ dinv,
                        const float* __restrict__ b1, const float* __restrict__ W2, float* __restrict__ h2p, int N) {
    __shared__ float sW2[16], sb1[16];
    if (threadIdx.x < 16) { sW2[threadIdx.x] = W2[threadIdx.x]; sb1[threadIdx.x] = b1[threadIdx.x]; }
    __syncthreads();
    int i = blockIdx.x * blockDim.x + threadIdx.x;
    if (i >= N) return;
    float di = dinv[i], self = di * di, a = 0.f;
#pragma unroll
    for (int ff = 0; ff < 16; ++ff) {
        float v = agg1[i * 16 + ff] + h1p[i * 16 + ff] * self + sb1[ff];
        a = fmaf(fmaxf(v, 0.f), sW2[ff], a);
    }
    h2p[i] = a;
}
__global__ void fb_sc2(const int* __restrict__ row, const int* __restrict__ col, const float* __restrict__ dinv,
                       const float* __restrict__ h2p, float* __restrict__ out, int E) {
    int stride = gridDim.x * blockDim.x;
    for (int e = blockIdx.x * blockDim.x + threadIdx.x; e < E; e += stride) {
        int r = row[e], c = col[e];
        atomicAdd(&out[c], h2p[r] * dinv[r] * dinv[c]);
    }
}
__global__ void fb_fin2(float* __restrict__ out, const float* __restrict__ h2p, const float* __restrict__ dinv,
                        const float* __restrict__ b2, int N) {
    int i = blockIdx.x * blockDim.x + threadIdx.x;
    if (i < N) {
        float di = dinv[i];
        out[i] = fmaxf(out[i] + h2p[i] * di * di + b2[0], 0.f);
    }
}

// ============================ launcher ============================

extern "C" void kernel_launch(void* const* d_in, const int* in_sizes, int n_in,
                              void* d_out, int out_size, void* d_ws, size_t ws_size,
                              hipStream_t stream) {
    const float* x  = (const float*)d_in[0];
    const int*   ei = (const int*)d_in[1];
    const float* W1 = (const float*)d_in[2];
    const float* b1 = (const float*)d_in[3];
    const float* W2 = (const float*)d_in[4];
    const float* b2 = (const float*)d_in[5];
    float* out = (float*)d_out;
    const int* row = ei;
    const int* col = ei + NE;
    char* ws = (char*)d_ws;

    constexpr size_t OFF_EB = 0;                          // 25,600,000 B
    constexpr size_t OFF_X  = 25600000;                   // 6,600,000 B region:
                                                          //   X (coarse bins, 800,768 B) — dead after passB2
                                                          //   g1h overlays X at +0 (3.2 MB, written by passS)
                                                          //   XF at +3,300,000 (25,024 B)
    constexpr size_t OFF_CT = OFF_X + 6600000;            // 4096 B (ctot, 98 used)
    constexpr size_t OFF_CB = OFF_CT + 4096;              // 4096 B (cbase)
    constexpr size_t OFF_DI = OFF_CB + 4096;              // 400,000 B
    constexpr size_t OFF_RS = OFF_DI + 400000;            // 400,128 B (rs[NN+1])
    constexpr size_t OFF_GG = OFF_RS + 400128;            // 400,000 B
    constexpr size_t WS_NEED = OFF_GG + 400000;           // ~33.4 MB (same as r9, proven)

    if (ws_size >= WS_NEED) {
        int*   eb    = (int*)(ws + OFF_EB);
        int*   X     = (int*)(ws + OFF_X);
        int*   XF    = (int*)(ws + OFF_X + 3300000);
        int*   ctot  = (int*)(ws + OFF_CT);
        int*   cbase = (int*)(ws + OFF_CB);
        float* dinv  = (float*)(ws + OFF_DI);
        int*   rs    = (int*)(ws + OFF_RS);
        float* gg    = (float*)(ws + OFF_GG);
        unsigned short* g1h = (unsigned short*)(ws + OFF_X);   // overlays X (dead after passB2)

        histA<<<NB, 512, 0, stream>>>(col, X);
        scan1<<<NCH, 512, 0, stream>>>(X, ctot);
        scan2<<<1, 1024, 0, stream>>>(ctot, cbase);
        scan3<<<(TOTB + 255) / 256, 256, 0, stream>>>(X, cbase);
        passB1<<<NB, 512, 0, stream>>>(row, col, X, eb);
        passB2<<<NCO, 256, 0, stream>>>(eb, X, XF);
        int gridK = (NBKT + 3) / 4;   // 1563
        passS<<<gridK, 256, 0, stream>>>(eb, XF, x, W1, dinv, rs, g1h);
        passE<<<gridK, 256, 0, stream>>>(eb, rs, g1h, dinv, b1, W2, gg);
        passF<<<gridK, 256, 0, stream>>>(eb, rs, gg, dinv, b2, out);
    } else {
        // fallback: global-atomic version (needs ~13.8 MB)
        float* dinv = (float*)(ws);
        float* h1p  = (float*)(ws + 524288);
        float* agg1 = (float*)(ws + 6924288);
        float* h2p  = (float*)(ws + 13324288);
        hipMemsetAsync(dinv, 0, NN * sizeof(float), stream);
        hipMemsetAsync(agg1, 0, NN * 16 * sizeof(float), stream);
        hipMemsetAsync(out, 0, NN * sizeof(float), stream);
        const int B = 256;
        int gridN = (NN + B - 1) / B;
        fb_deg<<<4096, B, 0, stream>>>(col, dinv, NE);
        fb_dinv<<<gridN, B, 0, stream>>>(dinv, NN);
        fb_h1p<<<gridN, B, 0, stream>>>(x, W1, h1p, NN);
        fb_sc1<<<8192, B, 0, stream>>>(row, col, dinv, h1p, agg1, (long)NE * 16);
        fb_fin1<<<gridN, B, 0, stream>>>(agg1, h1p, dinv, b1, W2, h2p, NN);
        fb_sc2<<<4096, B, 0, stream>>>(row, col, dinv, h2p, out, NE);
        fb_fin2<<<gridN, B, 0, stream>>>(out, h2p, dinv, b2, NN);
    }
}